// Round 1
// baseline (5122.801 us; speedup 1.0000x reference)
//
#include <hip/hip_runtime.h>

typedef _Float16 f16;
typedef f16 f16x8 __attribute__((ext_vector_type(8)));
typedef float f32x4 __attribute__((ext_vector_type(4)));
typedef const void __attribute__((address_space(1)))* gas1;
typedef void __attribute__((address_space(3)))* las3;

#define NB 4096
#define NN 21
#define MROWS (NB*NN)      // 86016
#define CIN 512
#define H1C 1024
#define H2C 1024
#define COUTC 512

// ---------------- adjacency ----------------
__global__ void k_adj(const float* __restrict__ nv1, const float* __restrict__ nv2,
                      float* __restrict__ Aout) {
  __shared__ float at[21][21];
  __shared__ float dinv[21];
  int t = threadIdx.x;
  if (t < 441) {
    int i = t / 21, j = t % 21;
    float s = 0.f;
    #pragma unroll
    for (int r = 0; r < 10; r++) s += nv1[i*10 + r] * nv2[r*21 + j];
    float v = 1.f / (1.f + expf(-s));
    if (i == j) v += 1.f;
    at[i][j] = v;
  }
  __syncthreads();
  if (t < 21) {
    float d = 0.f;
    #pragma unroll
    for (int j = 0; j < 21; j++) d += at[t][j];
    dinv[t] = d > 0.f ? rsqrtf(d) : 0.f;
  }
  __syncthreads();
  if (t < 441) {
    int i = t / 21, j = t % 21;
    float a = dinv[i] * at[i][j] * dinv[j];
    Aout[t] = a > 0.1f ? a : 0.f;
  }
}

// ---------------- transpose f32 [K][N] -> f16 [N][K] ----------------
__global__ void k_transpose(const float* __restrict__ src, f16* __restrict__ dst,
                            int K, int N) {
  __shared__ float tile[32][33];
  int n0 = blockIdx.x * 32, k0 = blockIdx.y * 32;
  int tx = threadIdx.x, ty = threadIdx.y;   // (32,8)
  #pragma unroll
  for (int i = 0; i < 4; i++)
    tile[ty + 8*i][tx] = src[(size_t)(k0 + ty + 8*i) * N + n0 + tx];
  __syncthreads();
  #pragma unroll
  for (int i = 0; i < 4; i++)
    dst[(size_t)(n0 + ty + 8*i) * K + k0 + tx] = (f16)tile[tx][ty + 8*i];
}

// ---------------- node mean over 21 ----------------
__global__ void k_mean(const float* __restrict__ x, float* __restrict__ xm) {
  int b = blockIdx.x, t = threadIdx.x;
  for (int c = t; c < CIN; c += 256) {
    float s = 0.f;
    #pragma unroll
    for (int n = 0; n < NN; n++) s += x[((size_t)b*NN + n)*CIN + c];
    xm[(size_t)b*CIN + c] = s * (1.f/21.f);
  }
}

// ---------------- SE matmuls ----------------
__global__ void k_se1(const float* __restrict__ xm, const float* __restrict__ w1,
                      float* __restrict__ y1) {
  __shared__ float row[CIN];
  int b = blockIdx.x, t = threadIdx.x;   // 128 threads
  for (int k = t; k < CIN; k += 128) row[k] = xm[(size_t)b*CIN + k];
  __syncthreads();
  float acc = 0.f;
  for (int k = 0; k < CIN; k++) acc += row[k] * w1[(size_t)k*128 + t];
  y1[(size_t)b*128 + t] = fmaxf(acc, 0.f);
}

__global__ void k_se2(const float* __restrict__ y1, const float* __restrict__ w2,
                      float* __restrict__ y) {
  __shared__ float row[128];
  int b = blockIdx.x, t = threadIdx.x;   // 512 threads
  if (t < 128) row[t] = y1[(size_t)b*128 + t];
  __syncthreads();
  float acc = 0.f;
  for (int k = 0; k < 128; k++) acc += row[k] * w2[(size_t)k*CIN + t];
  y[(size_t)b*CIN + t] = 1.f / (1.f + expf(-acc));
}

// ---------------- gating: xg = f16(x * y[graph]) ----------------
__global__ void k_gate(const float* __restrict__ x, const float* __restrict__ y,
                       f16* __restrict__ xg) {
  size_t i8 = (size_t)blockIdx.x * 256 + threadIdx.x;
  size_t base = i8 * 8;
  int r = (int)(base >> 9);          // /512
  int c = (int)(base & 511);
  int b = r / 21;
  const float4* xp = (const float4*)(x + base);
  const float4* yp = (const float4*)(y + (size_t)b*CIN + c);
  float4 a0 = xp[0], a1 = xp[1];
  float4 g0 = yp[0], g1 = yp[1];
  f16x8 o;
  o[0] = (f16)(a0.x * g0.x); o[1] = (f16)(a0.y * g0.y);
  o[2] = (f16)(a0.z * g0.z); o[3] = (f16)(a0.w * g0.w);
  o[4] = (f16)(a1.x * g1.x); o[5] = (f16)(a1.y * g1.y);
  o[6] = (f16)(a1.z * g1.z); o[7] = (f16)(a1.w * g1.w);
  *(f16x8*)(xg + base) = o;
}

// ---------------- GEMM: C[M][N] = A[M][K] @ BT[N][K]^T, f16 in, f16 out ----------------
__global__ __launch_bounds__(256)
void k_gemm(const f16* __restrict__ A, const f16* __restrict__ BT,
            f16* __restrict__ C, int M, int N, int K) {
  __shared__ __align__(16) f16 As[128*32];
  __shared__ __align__(16) f16 Bs[128*32];
  const int tid = threadIdx.x;
  const int bm = blockIdx.x, bn = blockIdx.y;
  const int lane = tid & 63;
  const int wr = (tid >> 7) & 1;
  const int wc = (tid >> 6) & 1;
  const int srow = tid >> 2;            // 0..63
  const int scol = (tid & 3) << 3;      // 0,8,16,24
  const f16* Ag = A + (size_t)(bm*128 + srow) * K + scol;
  const f16* Bg = BT + (size_t)(bn*128 + srow) * K + scol;
  f16* AsP = As + tid * 8;
  f16* BsP = Bs + tid * 8;
  const size_t rstep = (size_t)64 * K;

  const int fr = lane & 15;
  const int kg = (lane >> 4) << 3;
  const f16* ArP = As + (wr*64 + fr)*32 + kg;
  const f16* BrP = Bs + (wc*64 + fr)*32 + kg;

  f32x4 acc[4][4];
  #pragma unroll
  for (int m = 0; m < 4; m++)
    #pragma unroll
    for (int n = 0; n < 4; n++)
      #pragma unroll
      for (int r = 0; r < 4; r++) acc[m][n][r] = 0.f;

  for (int kt = 0; kt < K; kt += 32) {
    __builtin_amdgcn_global_load_lds((gas1)(Ag + kt),         (las3)AsP,            16, 0, 0);
    __builtin_amdgcn_global_load_lds((gas1)(Ag + kt + rstep), (las3)(AsP + 64*32),  16, 0, 0);
    __builtin_amdgcn_global_load_lds((gas1)(Bg + kt),         (las3)BsP,            16, 0, 0);
    __builtin_amdgcn_global_load_lds((gas1)(Bg + kt + rstep), (las3)(BsP + 64*32),  16, 0, 0);
    __syncthreads();
    f16x8 af[4], bv[4];
    #pragma unroll
    for (int m = 0; m < 4; m++) af[m] = *(const f16x8*)(ArP + m*16*32);
    #pragma unroll
    for (int n = 0; n < 4; n++) bv[n] = *(const f16x8*)(BrP + n*16*32);
    #pragma unroll
    for (int m = 0; m < 4; m++)
      #pragma unroll
      for (int n = 0; n < 4; n++)
        acc[m][n] = __builtin_amdgcn_mfma_f32_16x16x32_f16(af[m], bv[n], acc[m][n], 0, 0, 0);
    __syncthreads();
  }

  const int crow = bm*128 + wr*64 + ((lane >> 4) << 2);
  const int ccol = bn*128 + wc*64 + fr;
  #pragma unroll
  for (int m = 0; m < 4; m++)
    #pragma unroll
    for (int n = 0; n < 4; n++)
      #pragma unroll
      for (int r = 0; r < 4; r++)
        C[(size_t)(crow + m*16 + r) * N + (ccol + n*16)] = (f16)acc[m][n][r];
}

// ---------------- per-graph 21x21 mix, in-place, + bias ----------------
__global__ void k_mix(f16* __restrict__ t, const float* __restrict__ Aadj,
                      const float* __restrict__ bias, int C) {
  __shared__ float A[441];
  int b = blockIdx.x, tid = threadIdx.x;
  for (int i = tid; i < 441; i += 256) A[i] = Aadj[i];
  __syncthreads();
  size_t base = (size_t)b * NN * C;
  for (int c = tid; c < C; c += 256) {
    float v[21];
    #pragma unroll
    for (int j = 0; j < 21; j++) v[j] = (float)t[base + (size_t)j*C + c];
    float bb = bias[c];
    float o[21];
    #pragma unroll
    for (int i = 0; i < 21; i++) {
      float acc = bb;
      #pragma unroll
      for (int j = 0; j < 21; j++) acc += A[i*21 + j] * v[j];
      o[i] = acc;
    }
    #pragma unroll
    for (int i = 0; i < 21; i++) t[base + (size_t)i*C + c] = (f16)o[i];
  }
}

// ---------------- BN stats: per-block partial sums (deterministic) ----------------
__global__ void k_stats(const f16* __restrict__ g, float* __restrict__ psum,
                        float* __restrict__ psq, int C, int rows_per) {
  int c = blockIdx.x * 256 + threadIdx.x;
  int r0 = blockIdx.y * rows_per;
  float s = 0.f, q = 0.f;
  for (int r = 0; r < rows_per; r++) {
    float v = (float)g[(size_t)(r0 + r) * C + c];
    s += v; q += v * v;
  }
  psum[(size_t)blockIdx.y * C + c] = s;
  psq [(size_t)blockIdx.y * C + c] = q;
}

__global__ void k_bnparams(const float* __restrict__ psum, const float* __restrict__ psq,
                           const float* __restrict__ gamma, const float* __restrict__ beta,
                           const float* __restrict__ resbias,
                           float* __restrict__ scale, float* __restrict__ shift,
                           int C, int npart) {
  int c = blockIdx.x * 256 + threadIdx.x;
  float s = 0.f, q = 0.f;
  for (int p = 0; p < npart; p++) { s += psum[(size_t)p*C + c]; q += psq[(size_t)p*C + c]; }
  const float Minv = 1.f / (float)MROWS;
  float mean = s * Minv;
  float var = q * Minv - mean * mean;
  float sc = gamma[c] * rsqrtf(var + 1e-5f);
  float sh = beta[c] - mean * sc;
  if (resbias) sh += resbias[c];
  scale[c] = sc; shift[c] = sh;
}

// ---------------- finalize: dst = relu(g*scale + shift + res) ----------------
__global__ void k_finalize(const f16* __restrict__ g, const f16* __restrict__ res,
                           f16* __restrict__ dst, const float* __restrict__ scale,
                           const float* __restrict__ shift, int cmask) {
  size_t i8 = (size_t)blockIdx.x * 256 + threadIdx.x;
  size_t base = i8 * 8;
  int c = (int)(base & (size_t)cmask);
  f16x8 gv = *(const f16x8*)(g + base);
  f16x8 rv = *(const f16x8*)(res + base);
  f16x8 o;
  #pragma unroll
  for (int j = 0; j < 8; j++) {
    float v = (float)gv[j] * scale[c + j] + shift[c + j] + (float)rv[j];
    o[j] = (f16)fmaxf(v, 0.f);
  }
  *(f16x8*)(dst + base) = o;
}

// ---------------- pool (mean over 21) + BN affine ----------------
__global__ void k_pool(const f16* __restrict__ g3, const float* __restrict__ scale,
                       const float* __restrict__ shift, float* __restrict__ pooled) {
  int b = blockIdx.x, t = threadIdx.x;
  for (int c = t; c < COUTC; c += 256) {
    float s = 0.f;
    #pragma unroll
    for (int n = 0; n < NN; n++) s += (float)g3[((size_t)b*NN + n)*COUTC + c];
    pooled[(size_t)b*COUTC + c] = (s * (1.f/21.f)) * scale[c] + shift[c];
  }
}

// ---------------- final fc: out = pooled @ fc_w + fc_b ----------------
__global__ void k_fc(const float* __restrict__ pooled, const float* __restrict__ fcw,
                     const float* __restrict__ fcb, float* __restrict__ out) {
  __shared__ float row[COUTC];
  int b = blockIdx.x, t = threadIdx.x;  // 256
  for (int k = t; k < COUTC; k += 256) row[k] = pooled[(size_t)b*COUTC + k];
  __syncthreads();
  for (int o = t; o < 1024; o += 256) {
    float acc = fcb[o];
    for (int k = 0; k < COUTC; k++) acc += row[k] * fcw[(size_t)k*1024 + o];
    out[(size_t)b*1024 + o] = acc;
  }
}

extern "C" void kernel_launch(void* const* d_in, const int* in_sizes, int n_in,
                              void* d_out, int out_size, void* d_ws, size_t ws_size,
                              hipStream_t stream) {
  const float* x     = (const float*)d_in[0];
  const float* nv1   = (const float*)d_in[2];
  const float* nv2   = (const float*)d_in[3];
  const float* se_w1 = (const float*)d_in[4];
  const float* se_w2 = (const float*)d_in[5];
  const float* W1    = (const float*)d_in[6];
  const float* b1    = (const float*)d_in[7];
  const float* W2    = (const float*)d_in[8];
  const float* b2    = (const float*)d_in[9];
  const float* W3    = (const float*)d_in[10];
  const float* b3    = (const float*)d_in[11];
  const float* bn1g  = (const float*)d_in[12];
  const float* bn1b  = (const float*)d_in[13];
  const float* bn2g  = (const float*)d_in[14];
  const float* bn2b  = (const float*)d_in[15];
  const float* bn3g  = (const float*)d_in[16];
  const float* bn3b  = (const float*)d_in[17];
  const float* rs1w  = (const float*)d_in[18];
  const float* rs1b  = (const float*)d_in[19];
  const float* fcw   = (const float*)d_in[20];
  const float* fcb   = (const float*)d_in[21];
  float* out = (float*)d_out;

  char* ws = (char*)d_ws;
  size_t off = 0;
  auto alloc = [&](size_t bytes) -> char* {
    char* p = ws + off;
    off = (off + bytes + 255) & ~(size_t)255;
    return p;
  };

  float* A_adj = (float*)alloc(441 * 4);
  f16* W1T  = (f16*)alloc((size_t)H1C * CIN * 2);
  f16* RS1T = (f16*)alloc((size_t)H1C * CIN * 2);
  f16* W2T  = (f16*)alloc((size_t)H2C * H1C * 2);
  f16* W3T  = (f16*)alloc((size_t)COUTC * H2C * 2);
  float* xm = (float*)alloc((size_t)NB * CIN * 4);
  float* y1 = (float*)alloc((size_t)NB * 128 * 4);
  float* yv = (float*)alloc((size_t)NB * CIN * 4);
  float* psum = (float*)alloc((size_t)168 * 1024 * 4);
  float* psq  = (float*)alloc((size_t)168 * 1024 * 4);
  float* sc1 = (float*)alloc(1024 * 4);
  float* sh1 = (float*)alloc(1024 * 4);
  float* sc2 = (float*)alloc(1024 * 4);
  float* sh2 = (float*)alloc(1024 * 4);
  float* sc3 = (float*)alloc(1024 * 4);
  float* sh3 = (float*)alloc(1024 * 4);
  float* pooled = (float*)alloc((size_t)NB * COUTC * 4);
  f16* P1 = (f16*)alloc((size_t)MROWS * 512 * 2);    // xg -> t3/g3
  f16* P2 = (f16*)alloc((size_t)MROWS * 1024 * 2);   // t1/g1 -> t2/g2 -> h2
  f16* P3 = (f16*)alloc((size_t)MROWS * 1024 * 2);   // r1 -> h1
  (void)ws_size; (void)in_sizes; (void)n_in; (void)out_size;

  // adjacency + weight transposes
  k_adj<<<1, 512, 0, stream>>>(nv1, nv2, A_adj);
  k_transpose<<<dim3(32, 16), dim3(32, 8), 0, stream>>>(W1,   W1T,  512, 1024);
  k_transpose<<<dim3(32, 16), dim3(32, 8), 0, stream>>>(rs1w, RS1T, 512, 1024);
  k_transpose<<<dim3(32, 32), dim3(32, 8), 0, stream>>>(W2,   W2T,  1024, 1024);
  k_transpose<<<dim3(16, 32), dim3(32, 8), 0, stream>>>(W3,   W3T,  1024, 512);

  // SE path
  k_mean<<<NB, 256, 0, stream>>>(x, xm);
  k_se1<<<NB, 128, 0, stream>>>(xm, se_w1, y1);
  k_se2<<<NB, 512, 0, stream>>>(y1, se_w2, yv);
  k_gate<<<21504, 256, 0, stream>>>(x, yv, P1);

  // layer 1
  k_gemm<<<dim3(672, 8), 256, 0, stream>>>(P1, W1T,  P2, MROWS, 1024, 512);
  k_gemm<<<dim3(672, 8), 256, 0, stream>>>(P1, RS1T, P3, MROWS, 1024, 512);
  k_mix<<<NB, 256, 0, stream>>>(P2, A_adj, b1, 1024);
  k_stats<<<dim3(4, 168), 256, 0, stream>>>(P2, psum, psq, 1024, 512);
  k_bnparams<<<4, 256, 0, stream>>>(psum, psq, bn1g, bn1b, rs1b, sc1, sh1, 1024, 168);
  k_finalize<<<43008, 256, 0, stream>>>(P2, P3, P3, sc1, sh1, 1023);   // h1 -> P3

  // layer 2
  k_gemm<<<dim3(672, 8), 256, 0, stream>>>(P3, W2T, P2, MROWS, 1024, 1024);
  k_mix<<<NB, 256, 0, stream>>>(P2, A_adj, b2, 1024);
  k_stats<<<dim3(4, 168), 256, 0, stream>>>(P2, psum, psq, 1024, 512);
  k_bnparams<<<4, 256, 0, stream>>>(psum, psq, bn2g, bn2b, nullptr, sc2, sh2, 1024, 168);
  k_finalize<<<43008, 256, 0, stream>>>(P2, P3, P2, sc2, sh2, 1023);   // h2 -> P2

  // layer 3
  k_gemm<<<dim3(672, 4), 256, 0, stream>>>(P2, W3T, P1, MROWS, 512, 1024);
  k_mix<<<NB, 256, 0, stream>>>(P1, A_adj, b3, 512);
  k_stats<<<dim3(2, 168), 256, 0, stream>>>(P1, psum, psq, 512, 512);
  k_bnparams<<<2, 256, 0, stream>>>(psum, psq, bn3g, bn3b, nullptr, sc3, sh3, 512, 168);

  // pool + fc
  k_pool<<<NB, 256, 0, stream>>>(P1, sc3, sh3, pooled);
  k_fc<<<NB, 256, 0, stream>>>(pooled, fcw, fcb, out);
}

// Round 2
// 2427.871 us; speedup vs baseline: 2.1100x; 2.1100x over previous
//
#include <hip/hip_runtime.h>

typedef _Float16 f16;
typedef f16 f16x8 __attribute__((ext_vector_type(8)));
typedef float f32x4 __attribute__((ext_vector_type(4)));
typedef const void __attribute__((address_space(1)))* gas1;
typedef void __attribute__((address_space(3)))* las3;

#define NB 4096
#define NN 21
#define MROWS (NB*NN)      // 86016
#define CIN 512
#define H1C 1024
#define H2C 1024
#define COUTC 512

// ---------------- adjacency ----------------
__global__ void k_adj(const float* __restrict__ nv1, const float* __restrict__ nv2,
                      float* __restrict__ Aout) {
  __shared__ float at[21][21];
  __shared__ float dinv[21];
  int t = threadIdx.x;
  if (t < 441) {
    int i = t / 21, j = t % 21;
    float s = 0.f;
    #pragma unroll
    for (int r = 0; r < 10; r++) s += nv1[i*10 + r] * nv2[r*21 + j];
    float v = 1.f / (1.f + expf(-s));
    if (i == j) v += 1.f;
    at[i][j] = v;
  }
  __syncthreads();
  if (t < 21) {
    float d = 0.f;
    #pragma unroll
    for (int j = 0; j < 21; j++) d += at[t][j];
    dinv[t] = d > 0.f ? rsqrtf(d) : 0.f;
  }
  __syncthreads();
  if (t < 441) {
    int i = t / 21, j = t % 21;
    float a = dinv[i] * at[i][j] * dinv[j];
    Aout[t] = a > 0.1f ? a : 0.f;
  }
}

// ---------------- transpose f32 [K][N] -> f16 [N][K] ----------------
__global__ void k_transpose(const float* __restrict__ src, f16* __restrict__ dst,
                            int K, int N) {
  __shared__ float tile[32][33];
  int n0 = blockIdx.x * 32, k0 = blockIdx.y * 32;
  int tx = threadIdx.x, ty = threadIdx.y;   // (32,8)
  #pragma unroll
  for (int i = 0; i < 4; i++)
    tile[ty + 8*i][tx] = src[(size_t)(k0 + ty + 8*i) * N + n0 + tx];
  __syncthreads();
  #pragma unroll
  for (int i = 0; i < 4; i++)
    dst[(size_t)(n0 + ty + 8*i) * K + k0 + tx] = (f16)tile[tx][ty + 8*i];
}

// ---------------- node mean over 21 ----------------
__global__ void k_mean(const float* __restrict__ x, float* __restrict__ xm) {
  int b = blockIdx.x, t = threadIdx.x;
  for (int c = t; c < CIN; c += 256) {
    float s = 0.f;
    #pragma unroll
    for (int n = 0; n < NN; n++) s += x[((size_t)b*NN + n)*CIN + c];
    xm[(size_t)b*CIN + c] = s * (1.f/21.f);
  }
}

// ---------------- SE matmuls ----------------
__global__ void k_se1(const float* __restrict__ xm, const float* __restrict__ w1,
                      float* __restrict__ y1) {
  __shared__ float row[CIN];
  int b = blockIdx.x, t = threadIdx.x;   // 128 threads
  for (int k = t; k < CIN; k += 128) row[k] = xm[(size_t)b*CIN + k];
  __syncthreads();
  float acc = 0.f;
  for (int k = 0; k < CIN; k++) acc += row[k] * w1[(size_t)k*128 + t];
  y1[(size_t)b*128 + t] = fmaxf(acc, 0.f);
}

__global__ void k_se2(const float* __restrict__ y1, const float* __restrict__ w2,
                      float* __restrict__ y) {
  __shared__ float row[128];
  int b = blockIdx.x, t = threadIdx.x;   // 512 threads
  if (t < 128) row[t] = y1[(size_t)b*128 + t];
  __syncthreads();
  float acc = 0.f;
  for (int k = 0; k < 128; k++) acc += row[k] * w2[(size_t)k*CIN + t];
  y[(size_t)b*CIN + t] = 1.f / (1.f + expf(-acc));
}

// ---------------- gating: xg = f16(x * y[graph]) ----------------
__global__ void k_gate(const float* __restrict__ x, const float* __restrict__ y,
                       f16* __restrict__ xg) {
  size_t i8 = (size_t)blockIdx.x * 256 + threadIdx.x;
  size_t base = i8 * 8;
  int r = (int)(base >> 9);          // /512
  int c = (int)(base & 511);
  int b = r / 21;
  const float4* xp = (const float4*)(x + base);
  const float4* yp = (const float4*)(y + (size_t)b*CIN + c);
  float4 a0 = xp[0], a1 = xp[1];
  float4 g0 = yp[0], g1 = yp[1];
  f16x8 o;
  o[0] = (f16)(a0.x * g0.x); o[1] = (f16)(a0.y * g0.y);
  o[2] = (f16)(a0.z * g0.z); o[3] = (f16)(a0.w * g0.w);
  o[4] = (f16)(a1.x * g1.x); o[5] = (f16)(a1.y * g1.y);
  o[6] = (f16)(a1.z * g1.z); o[7] = (f16)(a1.w * g1.w);
  *(f16x8*)(xg + base) = o;
}

// ---------------- GEMM: C[M][N] = A[M][K] @ BT[N][K]^T, f16 in, f16 out ----------------
__global__ __launch_bounds__(256)
void k_gemm(const f16* __restrict__ A, const f16* __restrict__ BT,
            f16* __restrict__ C, int M, int N, int K) {
  __shared__ __align__(16) f16 As[128*32];
  __shared__ __align__(16) f16 Bs[128*32];
  const int tid = threadIdx.x;
  const int bm = blockIdx.x, bn = blockIdx.y;
  const int lane = tid & 63;
  const int wr = (tid >> 7) & 1;
  const int wc = (tid >> 6) & 1;
  const int srow = tid >> 2;            // 0..63
  const int scol = (tid & 3) << 3;      // 0,8,16,24
  const f16* Ag = A + (size_t)(bm*128 + srow) * K + scol;
  const f16* Bg = BT + (size_t)(bn*128 + srow) * K + scol;
  f16* AsP = As + tid * 8;
  f16* BsP = Bs + tid * 8;
  const size_t rstep = (size_t)64 * K;

  const int fr = lane & 15;
  const int kg = (lane >> 4) << 3;
  const f16* ArP = As + (wr*64 + fr)*32 + kg;
  const f16* BrP = Bs + (wc*64 + fr)*32 + kg;

  f32x4 acc[4][4];
  #pragma unroll
  for (int m = 0; m < 4; m++)
    #pragma unroll
    for (int n = 0; n < 4; n++)
      #pragma unroll
      for (int r = 0; r < 4; r++) acc[m][n][r] = 0.f;

  for (int kt = 0; kt < K; kt += 32) {
    __builtin_amdgcn_global_load_lds((gas1)(Ag + kt),         (las3)AsP,            16, 0, 0);
    __builtin_amdgcn_global_load_lds((gas1)(Ag + kt + rstep), (las3)(AsP + 64*32),  16, 0, 0);
    __builtin_amdgcn_global_load_lds((gas1)(Bg + kt),         (las3)BsP,            16, 0, 0);
    __builtin_amdgcn_global_load_lds((gas1)(Bg + kt + rstep), (las3)(BsP + 64*32),  16, 0, 0);
    __syncthreads();
    f16x8 af[4], bv[4];
    #pragma unroll
    for (int m = 0; m < 4; m++) af[m] = *(const f16x8*)(ArP + m*16*32);
    #pragma unroll
    for (int n = 0; n < 4; n++) bv[n] = *(const f16x8*)(BrP + n*16*32);
    #pragma unroll
    for (int m = 0; m < 4; m++)
      #pragma unroll
      for (int n = 0; n < 4; n++)
        acc[m][n] = __builtin_amdgcn_mfma_f32_16x16x32_f16(af[m], bv[n], acc[m][n], 0, 0, 0);
    __syncthreads();
  }

  const int crow = bm*128 + wr*64 + ((lane >> 4) << 2);
  const int ccol = bn*128 + wc*64 + fr;
  #pragma unroll
  for (int m = 0; m < 4; m++)
    #pragma unroll
    for (int n = 0; n < 4; n++)
      #pragma unroll
      for (int r = 0; r < 4; r++)
        C[(size_t)(crow + m*16 + r) * N + (ccol + n*16)] = (f16)acc[m][n][r];
}

// ---------------- per-graph 21x21 mix, in-place (bias absorbed by BN) ----------------
// 21 live floats per thread (was 42 -> spilled to scratch; 10x HBM over-traffic).
// Outputs are written immediately after each row's dot product.
__global__ __launch_bounds__(256)
void k_mix(f16* __restrict__ t, const float* __restrict__ Aadj, int C) {
  __shared__ float A[441];
  int b = blockIdx.x, tid = threadIdx.x;
  for (int i = tid; i < 441; i += 256) A[i] = Aadj[i];
  __syncthreads();
  size_t base = (size_t)b * NN * C;
  for (int c = tid; c < C; c += 256) {
    float v[21];
    #pragma unroll
    for (int j = 0; j < 21; j++) v[j] = (float)t[base + (size_t)j*C + c];
    #pragma unroll
    for (int i = 0; i < 21; i++) {
      float acc = 0.f;
      #pragma unroll
      for (int j = 0; j < 21; j++) acc = fmaf(A[i*21 + j], v[j], acc);
      t[base + (size_t)i*C + c] = (f16)acc;
    }
  }
}

// ---------------- BN stats: per-block partial sums (deterministic) ----------------
__global__ void k_stats(const f16* __restrict__ g, float* __restrict__ psum,
                        float* __restrict__ psq, int C, int rows_per) {
  int c = blockIdx.x * 256 + threadIdx.x;
  int r0 = blockIdx.y * rows_per;
  float s = 0.f, q = 0.f;
  for (int r = 0; r < rows_per; r++) {
    float v = (float)g[(size_t)(r0 + r) * C + c];
    s += v; q += v * v;
  }
  psum[(size_t)blockIdx.y * C + c] = s;
  psq [(size_t)blockIdx.y * C + c] = q;
}

__global__ void k_bnparams(const float* __restrict__ psum, const float* __restrict__ psq,
                           const float* __restrict__ gamma, const float* __restrict__ beta,
                           const float* __restrict__ resbias,
                           float* __restrict__ scale, float* __restrict__ shift,
                           int C, int npart) {
  int c = blockIdx.x * 256 + threadIdx.x;
  float s = 0.f, q = 0.f;
  for (int p = 0; p < npart; p++) { s += psum[(size_t)p*C + c]; q += psq[(size_t)p*C + c]; }
  const float Minv = 1.f / (float)MROWS;
  float mean = s * Minv;
  float var = q * Minv - mean * mean;
  float sc = gamma[c] * rsqrtf(var + 1e-5f);
  float sh = beta[c] - mean * sc;
  if (resbias) sh += resbias[c];
  scale[c] = sc; shift[c] = sh;
}

// ---------------- finalize: dst = relu(g*scale + shift + res) ----------------
__global__ void k_finalize(const f16* __restrict__ g, const f16* __restrict__ res,
                           f16* __restrict__ dst, const float* __restrict__ scale,
                           const float* __restrict__ shift, int cmask) {
  size_t i8 = (size_t)blockIdx.x * 256 + threadIdx.x;
  size_t base = i8 * 8;
  int c = (int)(base & (size_t)cmask);
  f16x8 gv = *(const f16x8*)(g + base);
  f16x8 rv = *(const f16x8*)(res + base);
  f16x8 o;
  #pragma unroll
  for (int j = 0; j < 8; j++) {
    float v = (float)gv[j] * scale[c + j] + shift[c + j] + (float)rv[j];
    o[j] = (f16)fmaxf(v, 0.f);
  }
  *(f16x8*)(dst + base) = o;
}

// ---------------- pool (mean over 21) + BN affine ----------------
__global__ void k_pool(const f16* __restrict__ g3, const float* __restrict__ scale,
                       const float* __restrict__ shift, float* __restrict__ pooled) {
  int b = blockIdx.x, t = threadIdx.x;
  for (int c = t; c < COUTC; c += 256) {
    float s = 0.f;
    #pragma unroll
    for (int n = 0; n < NN; n++) s += (float)g3[((size_t)b*NN + n)*COUTC + c];
    pooled[(size_t)b*COUTC + c] = (s * (1.f/21.f)) * scale[c] + shift[c];
  }
}

// ---------------- final fc: out = pooled @ fc_w + fc_b ----------------
__global__ void k_fc(const float* __restrict__ pooled, const float* __restrict__ fcw,
                     const float* __restrict__ fcb, float* __restrict__ out) {
  __shared__ float row[COUTC];
  int b = blockIdx.x, t = threadIdx.x;  // 256
  for (int k = t; k < COUTC; k += 256) row[k] = pooled[(size_t)b*COUTC + k];
  __syncthreads();
  for (int o = t; o < 1024; o += 256) {
    float acc = fcb[o];
    for (int k = 0; k < COUTC; k++) acc += row[k] * fcw[(size_t)k*1024 + o];
    out[(size_t)b*1024 + o] = acc;
  }
}

extern "C" void kernel_launch(void* const* d_in, const int* in_sizes, int n_in,
                              void* d_out, int out_size, void* d_ws, size_t ws_size,
                              hipStream_t stream) {
  const float* x     = (const float*)d_in[0];
  const float* nv1   = (const float*)d_in[2];
  const float* nv2   = (const float*)d_in[3];
  const float* se_w1 = (const float*)d_in[4];
  const float* se_w2 = (const float*)d_in[5];
  const float* W1    = (const float*)d_in[6];
  const float* W2    = (const float*)d_in[8];
  const float* W3    = (const float*)d_in[10];
  const float* bn1g  = (const float*)d_in[12];
  const float* bn1b  = (const float*)d_in[13];
  const float* bn2g  = (const float*)d_in[14];
  const float* bn2b  = (const float*)d_in[15];
  const float* bn3g  = (const float*)d_in[16];
  const float* bn3b  = (const float*)d_in[17];
  const float* rs1w  = (const float*)d_in[18];
  const float* rs1b  = (const float*)d_in[19];
  const float* fcw   = (const float*)d_in[20];
  const float* fcb   = (const float*)d_in[21];
  float* out = (float*)d_out;

  char* ws = (char*)d_ws;
  size_t off = 0;
  auto alloc = [&](size_t bytes) -> char* {
    char* p = ws + off;
    off = (off + bytes + 255) & ~(size_t)255;
    return p;
  };

  float* A_adj = (float*)alloc(441 * 4);
  f16* W1T  = (f16*)alloc((size_t)H1C * CIN * 2);
  f16* RS1T = (f16*)alloc((size_t)H1C * CIN * 2);
  f16* W2T  = (f16*)alloc((size_t)H2C * H1C * 2);
  f16* W3T  = (f16*)alloc((size_t)COUTC * H2C * 2);
  float* xm = (float*)alloc((size_t)NB * CIN * 4);
  float* y1 = (float*)alloc((size_t)NB * 128 * 4);
  float* yv = (float*)alloc((size_t)NB * CIN * 4);
  float* psum = (float*)alloc((size_t)168 * 1024 * 4);
  float* psq  = (float*)alloc((size_t)168 * 1024 * 4);
  float* sc1 = (float*)alloc(1024 * 4);
  float* sh1 = (float*)alloc(1024 * 4);
  float* sc2 = (float*)alloc(1024 * 4);
  float* sh2 = (float*)alloc(1024 * 4);
  float* sc3 = (float*)alloc(1024 * 4);
  float* sh3 = (float*)alloc(1024 * 4);
  float* pooled = (float*)alloc((size_t)NB * COUTC * 4);
  f16* P1 = (f16*)alloc((size_t)MROWS * 512 * 2);    // xg -> t3/g3
  f16* P2 = (f16*)alloc((size_t)MROWS * 1024 * 2);   // t1/g1 -> t2/g2 -> h2
  f16* P3 = (f16*)alloc((size_t)MROWS * 1024 * 2);   // r1 -> h1
  (void)ws_size; (void)in_sizes; (void)n_in; (void)out_size;

  // adjacency + weight transposes
  k_adj<<<1, 512, 0, stream>>>(nv1, nv2, A_adj);
  k_transpose<<<dim3(32, 16), dim3(32, 8), 0, stream>>>(W1,   W1T,  512, 1024);
  k_transpose<<<dim3(32, 16), dim3(32, 8), 0, stream>>>(rs1w, RS1T, 512, 1024);
  k_transpose<<<dim3(32, 32), dim3(32, 8), 0, stream>>>(W2,   W2T,  1024, 1024);
  k_transpose<<<dim3(16, 32), dim3(32, 8), 0, stream>>>(W3,   W3T,  1024, 512);

  // SE path
  k_mean<<<NB, 256, 0, stream>>>(x, xm);
  k_se1<<<NB, 128, 0, stream>>>(xm, se_w1, y1);
  k_se2<<<NB, 512, 0, stream>>>(y1, se_w2, yv);
  k_gate<<<21504, 256, 0, stream>>>(x, yv, P1);

  // layer 1
  k_gemm<<<dim3(672, 8), 256, 0, stream>>>(P1, W1T,  P2, MROWS, 1024, 512);
  k_gemm<<<dim3(672, 8), 256, 0, stream>>>(P1, RS1T, P3, MROWS, 1024, 512);
  k_mix<<<NB, 256, 0, stream>>>(P2, A_adj, 1024);
  k_stats<<<dim3(4, 168), 256, 0, stream>>>(P2, psum, psq, 1024, 512);
  k_bnparams<<<4, 256, 0, stream>>>(psum, psq, bn1g, bn1b, rs1b, sc1, sh1, 1024, 168);
  k_finalize<<<43008, 256, 0, stream>>>(P2, P3, P3, sc1, sh1, 1023);   // h1 -> P3

  // layer 2
  k_gemm<<<dim3(672, 8), 256, 0, stream>>>(P3, W2T, P2, MROWS, 1024, 1024);
  k_mix<<<NB, 256, 0, stream>>>(P2, A_adj, 1024);
  k_stats<<<dim3(4, 168), 256, 0, stream>>>(P2, psum, psq, 1024, 512);
  k_bnparams<<<4, 256, 0, stream>>>(psum, psq, bn2g, bn2b, nullptr, sc2, sh2, 1024, 168);
  k_finalize<<<43008, 256, 0, stream>>>(P2, P3, P2, sc2, sh2, 1023);   // h2 -> P2

  // layer 3
  k_gemm<<<dim3(672, 4), 256, 0, stream>>>(P2, W3T, P1, MROWS, 512, 1024);
  k_mix<<<NB, 256, 0, stream>>>(P1, A_adj, 512);
  k_stats<<<dim3(2, 168), 256, 0, stream>>>(P1, psum, psq, 512, 512);
  k_bnparams<<<2, 256, 0, stream>>>(psum, psq, bn3g, bn3b, nullptr, sc3, sh3, 512, 168);

  // pool + fc
  k_pool<<<NB, 256, 0, stream>>>(P1, sc3, sh3, pooled);
  k_fc<<<NB, 256, 0, stream>>>(pooled, fcw, fcb, out);
}

// Round 3
// 2136.598 us; speedup vs baseline: 2.3976x; 1.1363x over previous
//
#include <hip/hip_runtime.h>

typedef _Float16 f16;
typedef f16 f16x8 __attribute__((ext_vector_type(8)));
typedef float f32x4 __attribute__((ext_vector_type(4)));
typedef const void __attribute__((address_space(1)))* gas1;
typedef void __attribute__((address_space(3)))* las3;

#define NB 4096
#define NN 21
#define MROWS (NB*NN)      // 86016
#define CIN 512
#define H1C 1024
#define H2C 1024
#define COUTC 512

// ---------------- adjacency ----------------
__global__ void k_adj(const float* __restrict__ nv1, const float* __restrict__ nv2,
                      float* __restrict__ Aout) {
  __shared__ float at[21][21];
  __shared__ float dinv[21];
  int t = threadIdx.x;
  if (t < 441) {
    int i = t / 21, j = t % 21;
    float s = 0.f;
    #pragma unroll
    for (int r = 0; r < 10; r++) s += nv1[i*10 + r] * nv2[r*21 + j];
    float v = 1.f / (1.f + expf(-s));
    if (i == j) v += 1.f;
    at[i][j] = v;
  }
  __syncthreads();
  if (t < 21) {
    float d = 0.f;
    #pragma unroll
    for (int j = 0; j < 21; j++) d += at[t][j];
    dinv[t] = d > 0.f ? rsqrtf(d) : 0.f;
  }
  __syncthreads();
  if (t < 441) {
    int i = t / 21, j = t % 21;
    float a = dinv[i] * at[i][j] * dinv[j];
    Aout[t] = a > 0.1f ? a : 0.f;
  }
}

// ---------------- transpose f32 [K][N] -> f16 [N][K] ----------------
__global__ void k_transpose(const float* __restrict__ src, f16* __restrict__ dst,
                            int K, int N) {
  __shared__ float tile[32][33];
  int n0 = blockIdx.x * 32, k0 = blockIdx.y * 32;
  int tx = threadIdx.x, ty = threadIdx.y;   // (32,8)
  #pragma unroll
  for (int i = 0; i < 4; i++)
    tile[ty + 8*i][tx] = src[(size_t)(k0 + ty + 8*i) * N + n0 + tx];
  __syncthreads();
  #pragma unroll
  for (int i = 0; i < 4; i++)
    dst[(size_t)(n0 + ty + 8*i) * K + k0 + tx] = (f16)tile[tx][ty + 8*i];
}

// ---------------- node mean over 21 ----------------
__global__ void k_mean(const float* __restrict__ x, float* __restrict__ xm) {
  int b = blockIdx.x, t = threadIdx.x;
  for (int c = t; c < CIN; c += 256) {
    float s = 0.f;
    #pragma unroll
    for (int n = 0; n < NN; n++) s += x[((size_t)b*NN + n)*CIN + c];
    xm[(size_t)b*CIN + c] = s * (1.f/21.f);
  }
}

// ---------------- SE matmuls ----------------
__global__ void k_se1(const float* __restrict__ xm, const float* __restrict__ w1,
                      float* __restrict__ y1) {
  __shared__ float row[CIN];
  int b = blockIdx.x, t = threadIdx.x;   // 128 threads
  for (int k = t; k < CIN; k += 128) row[k] = xm[(size_t)b*CIN + k];
  __syncthreads();
  float acc = 0.f;
  for (int k = 0; k < CIN; k++) acc += row[k] * w1[(size_t)k*128 + t];
  y1[(size_t)b*128 + t] = fmaxf(acc, 0.f);
}

__global__ void k_se2(const float* __restrict__ y1, const float* __restrict__ w2,
                      float* __restrict__ y) {
  __shared__ float row[128];
  int b = blockIdx.x, t = threadIdx.x;   // 512 threads
  if (t < 128) row[t] = y1[(size_t)b*128 + t];
  __syncthreads();
  float acc = 0.f;
  for (int k = 0; k < 128; k++) acc += row[k] * w2[(size_t)k*CIN + t];
  y[(size_t)b*CIN + t] = 1.f / (1.f + expf(-acc));
}

// ---------------- gating: xg = f16(x * y[graph]) ----------------
__global__ void k_gate(const float* __restrict__ x, const float* __restrict__ y,
                       f16* __restrict__ xg) {
  size_t i8 = (size_t)blockIdx.x * 256 + threadIdx.x;
  size_t base = i8 * 8;
  int r = (int)(base >> 9);          // /512
  int c = (int)(base & 511);
  int b = r / 21;
  const float4* xp = (const float4*)(x + base);
  const float4* yp = (const float4*)(y + (size_t)b*CIN + c);
  float4 a0 = xp[0], a1 = xp[1];
  float4 g0 = yp[0], g1 = yp[1];
  f16x8 o;
  o[0] = (f16)(a0.x * g0.x); o[1] = (f16)(a0.y * g0.y);
  o[2] = (f16)(a0.z * g0.z); o[3] = (f16)(a0.w * g0.w);
  o[4] = (f16)(a1.x * g1.x); o[5] = (f16)(a1.y * g1.y);
  o[6] = (f16)(a1.z * g1.z); o[7] = (f16)(a1.w * g1.w);
  *(f16x8*)(xg + base) = o;
}

// ---------------- GEMM: C[M][N] = A[M][K] @ BT[N][K]^T, f16 in, f16 out ----------------
__global__ __launch_bounds__(256)
void k_gemm(const f16* __restrict__ A, const f16* __restrict__ BT,
            f16* __restrict__ C, int M, int N, int K) {
  __shared__ __align__(16) f16 As[128*32];
  __shared__ __align__(16) f16 Bs[128*32];
  const int tid = threadIdx.x;
  const int bm = blockIdx.x, bn = blockIdx.y;
  const int lane = tid & 63;
  const int wr = (tid >> 7) & 1;
  const int wc = (tid >> 6) & 1;
  const int srow = tid >> 2;            // 0..63
  const int scol = (tid & 3) << 3;      // 0,8,16,24
  const f16* Ag = A + (size_t)(bm*128 + srow) * K + scol;
  const f16* Bg = BT + (size_t)(bn*128 + srow) * K + scol;
  f16* AsP = As + tid * 8;
  f16* BsP = Bs + tid * 8;
  const size_t rstep = (size_t)64 * K;

  const int fr = lane & 15;
  const int kg = (lane >> 4) << 3;
  const f16* ArP = As + (wr*64 + fr)*32 + kg;
  const f16* BrP = Bs + (wc*64 + fr)*32 + kg;

  f32x4 acc[4][4];
  #pragma unroll
  for (int m = 0; m < 4; m++)
    #pragma unroll
    for (int n = 0; n < 4; n++)
      #pragma unroll
      for (int r = 0; r < 4; r++) acc[m][n][r] = 0.f;

  for (int kt = 0; kt < K; kt += 32) {
    __builtin_amdgcn_global_load_lds((gas1)(Ag + kt),         (las3)AsP,            16, 0, 0);
    __builtin_amdgcn_global_load_lds((gas1)(Ag + kt + rstep), (las3)(AsP + 64*32),  16, 0, 0);
    __builtin_amdgcn_global_load_lds((gas1)(Bg + kt),         (las3)BsP,            16, 0, 0);
    __builtin_amdgcn_global_load_lds((gas1)(Bg + kt + rstep), (las3)(BsP + 64*32),  16, 0, 0);
    __syncthreads();
    f16x8 af[4], bv[4];
    #pragma unroll
    for (int m = 0; m < 4; m++) af[m] = *(const f16x8*)(ArP + m*16*32);
    #pragma unroll
    for (int n = 0; n < 4; n++) bv[n] = *(const f16x8*)(BrP + n*16*32);
    #pragma unroll
    for (int m = 0; m < 4; m++)
      #pragma unroll
      for (int n = 0; n < 4; n++)
        acc[m][n] = __builtin_amdgcn_mfma_f32_16x16x32_f16(af[m], bv[n], acc[m][n], 0, 0, 0);
    __syncthreads();
  }

  const int crow = bm*128 + wr*64 + ((lane >> 4) << 2);
  const int ccol = bn*128 + wc*64 + fr;
  #pragma unroll
  for (int m = 0; m < 4; m++)
    #pragma unroll
    for (int n = 0; n < 4; n++)
      #pragma unroll
      for (int r = 0; r < 4; r++)
        C[(size_t)(crow + m*16 + r) * N + (ccol + n*16)] = (f16)acc[m][n][r];
}

// ---------------- GEMM variant: f32 output + bias (final fc) ----------------
__global__ __launch_bounds__(256)
void k_gemm_fc(const f16* __restrict__ A, const f16* __restrict__ BT,
               const float* __restrict__ bias, float* __restrict__ C,
               int M, int N, int K) {
  __shared__ __align__(16) f16 As[128*32];
  __shared__ __align__(16) f16 Bs[128*32];
  const int tid = threadIdx.x;
  const int bm = blockIdx.x, bn = blockIdx.y;
  const int lane = tid & 63;
  const int wr = (tid >> 7) & 1;
  const int wc = (tid >> 6) & 1;
  const int srow = tid >> 2;
  const int scol = (tid & 3) << 3;
  const f16* Ag = A + (size_t)(bm*128 + srow) * K + scol;
  const f16* Bg = BT + (size_t)(bn*128 + srow) * K + scol;
  f16* AsP = As + tid * 8;
  f16* BsP = Bs + tid * 8;
  const size_t rstep = (size_t)64 * K;

  const int fr = lane & 15;
  const int kg = (lane >> 4) << 3;
  const f16* ArP = As + (wr*64 + fr)*32 + kg;
  const f16* BrP = Bs + (wc*64 + fr)*32 + kg;

  f32x4 acc[4][4];
  #pragma unroll
  for (int m = 0; m < 4; m++)
    #pragma unroll
    for (int n = 0; n < 4; n++)
      #pragma unroll
      for (int r = 0; r < 4; r++) acc[m][n][r] = 0.f;

  for (int kt = 0; kt < K; kt += 32) {
    __builtin_amdgcn_global_load_lds((gas1)(Ag + kt),         (las3)AsP,            16, 0, 0);
    __builtin_amdgcn_global_load_lds((gas1)(Ag + kt + rstep), (las3)(AsP + 64*32),  16, 0, 0);
    __builtin_amdgcn_global_load_lds((gas1)(Bg + kt),         (las3)BsP,            16, 0, 0);
    __builtin_amdgcn_global_load_lds((gas1)(Bg + kt + rstep), (las3)(BsP + 64*32),  16, 0, 0);
    __syncthreads();
    f16x8 af[4], bv[4];
    #pragma unroll
    for (int m = 0; m < 4; m++) af[m] = *(const f16x8*)(ArP + m*16*32);
    #pragma unroll
    for (int n = 0; n < 4; n++) bv[n] = *(const f16x8*)(BrP + n*16*32);
    #pragma unroll
    for (int m = 0; m < 4; m++)
      #pragma unroll
      for (int n = 0; n < 4; n++)
        acc[m][n] = __builtin_amdgcn_mfma_f32_16x16x32_f16(af[m], bv[n], acc[m][n], 0, 0, 0);
    __syncthreads();
  }

  const int crow = bm*128 + wr*64 + ((lane >> 4) << 2);
  const int ccol = bn*128 + wc*64 + fr;
  #pragma unroll
  for (int n = 0; n < 4; n++) {
    float bb = bias[ccol + n*16];
    #pragma unroll
    for (int m = 0; m < 4; m++)
      #pragma unroll
      for (int r = 0; r < 4; r++)
        C[(size_t)(crow + m*16 + r) * N + (ccol + n*16)] = acc[m][n][r] + bb;
  }
}

// ---------------- per-graph 21x21 mix, in-place (bias absorbed by BN) ----------------
__global__ __launch_bounds__(256)
void k_mix(f16* __restrict__ t, const float* __restrict__ Aadj, int C) {
  __shared__ float A[441];
  int b = blockIdx.x, tid = threadIdx.x;
  for (int i = tid; i < 441; i += 256) A[i] = Aadj[i];
  __syncthreads();
  size_t base = (size_t)b * NN * C;
  for (int c = tid; c < C; c += 256) {
    float v[21];
    #pragma unroll
    for (int j = 0; j < 21; j++) v[j] = (float)t[base + (size_t)j*C + c];
    #pragma unroll
    for (int i = 0; i < 21; i++) {
      float acc = 0.f;
      #pragma unroll
      for (int j = 0; j < 21; j++) acc = fmaf(A[i*21 + j], v[j], acc);
      t[base + (size_t)i*C + c] = (f16)acc;
    }
  }
}

// ---------------- BN stats: per-block partial sums (deterministic) ----------------
__global__ void k_stats(const f16* __restrict__ g, float* __restrict__ psum,
                        float* __restrict__ psq, int C, int rows_per) {
  int c = blockIdx.x * 256 + threadIdx.x;
  int r0 = blockIdx.y * rows_per;
  float s = 0.f, q = 0.f;
  for (int r = 0; r < rows_per; r++) {
    float v = (float)g[(size_t)(r0 + r) * C + c];
    s += v; q += v * v;
  }
  psum[(size_t)blockIdx.y * C + c] = s;
  psq [(size_t)blockIdx.y * C + c] = q;
}

__global__ void k_bnparams(const float* __restrict__ psum, const float* __restrict__ psq,
                           const float* __restrict__ gamma, const float* __restrict__ beta,
                           const float* __restrict__ resbias,
                           float* __restrict__ scale, float* __restrict__ shift,
                           int C, int npart) {
  int c = blockIdx.x * 256 + threadIdx.x;
  float s = 0.f, q = 0.f;
  for (int p = 0; p < npart; p++) { s += psum[(size_t)p*C + c]; q += psq[(size_t)p*C + c]; }
  const float Minv = 1.f / (float)MROWS;
  float mean = s * Minv;
  float var = q * Minv - mean * mean;
  float sc = gamma[c] * rsqrtf(var + 1e-5f);
  float sh = beta[c] - mean * sc;
  if (resbias) sh += resbias[c];
  scale[c] = sc; shift[c] = sh;
}

// ---------------- finalize: dst = relu(g*scale + shift + res) ----------------
__global__ void k_finalize(const f16* __restrict__ g, const f16* __restrict__ res,
                           f16* __restrict__ dst, const float* __restrict__ scale,
                           const float* __restrict__ shift, int cmask) {
  size_t i8 = (size_t)blockIdx.x * 256 + threadIdx.x;
  size_t base = i8 * 8;
  int c = (int)(base & (size_t)cmask);
  f16x8 gv = *(const f16x8*)(g + base);
  f16x8 rv = *(const f16x8*)(res + base);
  f16x8 o;
  #pragma unroll
  for (int j = 0; j < 8; j++) {
    float v = (float)gv[j] * scale[c + j] + shift[c + j] + (float)rv[j];
    o[j] = (f16)fmaxf(v, 0.f);
  }
  *(f16x8*)(dst + base) = o;
}

// ---------------- pool (mean over 21) + BN affine -> f16 ----------------
__global__ void k_pool(const f16* __restrict__ g3, const float* __restrict__ scale,
                       const float* __restrict__ shift, f16* __restrict__ pooled) {
  int b = blockIdx.x, t = threadIdx.x;
  for (int c = t; c < COUTC; c += 256) {
    float s = 0.f;
    #pragma unroll
    for (int n = 0; n < NN; n++) s += (float)g3[((size_t)b*NN + n)*COUTC + c];
    pooled[(size_t)b*COUTC + c] = (f16)((s * (1.f/21.f)) * scale[c] + shift[c]);
  }
}

extern "C" void kernel_launch(void* const* d_in, const int* in_sizes, int n_in,
                              void* d_out, int out_size, void* d_ws, size_t ws_size,
                              hipStream_t stream) {
  const float* x     = (const float*)d_in[0];
  const float* nv1   = (const float*)d_in[2];
  const float* nv2   = (const float*)d_in[3];
  const float* se_w1 = (const float*)d_in[4];
  const float* se_w2 = (const float*)d_in[5];
  const float* W1    = (const float*)d_in[6];
  const float* W2    = (const float*)d_in[8];
  const float* W3    = (const float*)d_in[10];
  const float* bn1g  = (const float*)d_in[12];
  const float* bn1b  = (const float*)d_in[13];
  const float* bn2g  = (const float*)d_in[14];
  const float* bn2b  = (const float*)d_in[15];
  const float* bn3g  = (const float*)d_in[16];
  const float* bn3b  = (const float*)d_in[17];
  const float* rs1w  = (const float*)d_in[18];
  const float* rs1b  = (const float*)d_in[19];
  const float* fcw   = (const float*)d_in[20];
  const float* fcb   = (const float*)d_in[21];
  float* out = (float*)d_out;

  char* ws = (char*)d_ws;
  size_t off = 0;
  auto alloc = [&](size_t bytes) -> char* {
    char* p = ws + off;
    off = (off + bytes + 255) & ~(size_t)255;
    return p;
  };

  float* A_adj = (float*)alloc(441 * 4);
  f16* W1T  = (f16*)alloc((size_t)H1C * CIN * 2);
  f16* RS1T = (f16*)alloc((size_t)H1C * CIN * 2);
  f16* W2T  = (f16*)alloc((size_t)H2C * H1C * 2);
  f16* W3T  = (f16*)alloc((size_t)COUTC * H2C * 2);
  f16* FCWT = (f16*)alloc((size_t)1024 * COUTC * 2);
  float* xm = (float*)alloc((size_t)NB * CIN * 4);
  float* y1 = (float*)alloc((size_t)NB * 128 * 4);
  float* yv = (float*)alloc((size_t)NB * CIN * 4);
  float* psum = (float*)alloc((size_t)168 * 1024 * 4);
  float* psq  = (float*)alloc((size_t)168 * 1024 * 4);
  float* sc1 = (float*)alloc(1024 * 4);
  float* sh1 = (float*)alloc(1024 * 4);
  float* sc2 = (float*)alloc(1024 * 4);
  float* sh2 = (float*)alloc(1024 * 4);
  float* sc3 = (float*)alloc(1024 * 4);
  float* sh3 = (float*)alloc(1024 * 4);
  f16* pooled = (f16*)alloc((size_t)NB * COUTC * 2);
  f16* P1 = (f16*)alloc((size_t)MROWS * 512 * 2);    // xg -> t3/g3
  f16* P2 = (f16*)alloc((size_t)MROWS * 1024 * 2);   // t1/g1 -> t2/g2 -> h2
  f16* P3 = (f16*)alloc((size_t)MROWS * 1024 * 2);   // r1 -> h1
  (void)ws_size; (void)in_sizes; (void)n_in; (void)out_size;

  // adjacency + weight transposes
  k_adj<<<1, 512, 0, stream>>>(nv1, nv2, A_adj);
  k_transpose<<<dim3(32, 16), dim3(32, 8), 0, stream>>>(W1,   W1T,  512, 1024);
  k_transpose<<<dim3(32, 16), dim3(32, 8), 0, stream>>>(rs1w, RS1T, 512, 1024);
  k_transpose<<<dim3(32, 32), dim3(32, 8), 0, stream>>>(W2,   W2T,  1024, 1024);
  k_transpose<<<dim3(16, 32), dim3(32, 8), 0, stream>>>(W3,   W3T,  1024, 512);
  k_transpose<<<dim3(32, 16), dim3(32, 8), 0, stream>>>(fcw,  FCWT, 512, 1024);

  // SE path
  k_mean<<<NB, 256, 0, stream>>>(x, xm);
  k_se1<<<NB, 128, 0, stream>>>(xm, se_w1, y1);
  k_se2<<<NB, 512, 0, stream>>>(y1, se_w2, yv);
  k_gate<<<21504, 256, 0, stream>>>(x, yv, P1);

  // layer 1
  k_gemm<<<dim3(672, 8), 256, 0, stream>>>(P1, W1T,  P2, MROWS, 1024, 512);
  k_gemm<<<dim3(672, 8), 256, 0, stream>>>(P1, RS1T, P3, MROWS, 1024, 512);
  k_mix<<<NB, 256, 0, stream>>>(P2, A_adj, 1024);
  k_stats<<<dim3(4, 168), 256, 0, stream>>>(P2, psum, psq, 1024, 512);
  k_bnparams<<<4, 256, 0, stream>>>(psum, psq, bn1g, bn1b, rs1b, sc1, sh1, 1024, 168);
  k_finalize<<<43008, 256, 0, stream>>>(P2, P3, P3, sc1, sh1, 1023);   // h1 -> P3

  // layer 2
  k_gemm<<<dim3(672, 8), 256, 0, stream>>>(P3, W2T, P2, MROWS, 1024, 1024);
  k_mix<<<NB, 256, 0, stream>>>(P2, A_adj, 1024);
  k_stats<<<dim3(4, 168), 256, 0, stream>>>(P2, psum, psq, 1024, 512);
  k_bnparams<<<4, 256, 0, stream>>>(psum, psq, bn2g, bn2b, nullptr, sc2, sh2, 1024, 168);
  k_finalize<<<43008, 256, 0, stream>>>(P2, P3, P2, sc2, sh2, 1023);   // h2 -> P2

  // layer 3
  k_gemm<<<dim3(672, 4), 256, 0, stream>>>(P2, W3T, P1, MROWS, 512, 1024);
  k_mix<<<NB, 256, 0, stream>>>(P1, A_adj, 512);
  k_stats<<<dim3(2, 168), 256, 0, stream>>>(P1, psum, psq, 512, 512);
  k_bnparams<<<2, 256, 0, stream>>>(psum, psq, bn3g, bn3b, nullptr, sc3, sh3, 512, 168);

  // pool + fc (MFMA)
  k_pool<<<NB, 256, 0, stream>>>(P1, sc3, sh3, pooled);
  k_gemm_fc<<<dim3(32, 8), 256, 0, stream>>>(pooled, FCWT, fcb, out, NB, 1024, COUTC);
}

// Round 4
// 1907.933 us; speedup vs baseline: 2.6850x; 1.1198x over previous
//
#include <hip/hip_runtime.h>

typedef _Float16 f16;
typedef f16 f16x8 __attribute__((ext_vector_type(8)));
typedef float f32x4 __attribute__((ext_vector_type(4)));
typedef const void __attribute__((address_space(1)))* gas1;
typedef void __attribute__((address_space(3)))* las3;

#define NB 4096
#define NN 21
#define MROWS (NB*NN)      // 86016
#define CIN 512
#define H1C 1024
#define H2C 1024
#define COUTC 512

// ---------------- adjacency ----------------
__global__ void k_adj(const float* __restrict__ nv1, const float* __restrict__ nv2,
                      float* __restrict__ Aout) {
  __shared__ float at[21][21];
  __shared__ float dinv[21];
  int t = threadIdx.x;
  if (t < 441) {
    int i = t / 21, j = t % 21;
    float s = 0.f;
    #pragma unroll
    for (int r = 0; r < 10; r++) s += nv1[i*10 + r] * nv2[r*21 + j];
    float v = 1.f / (1.f + expf(-s));
    if (i == j) v += 1.f;
    at[i][j] = v;
  }
  __syncthreads();
  if (t < 21) {
    float d = 0.f;
    #pragma unroll
    for (int j = 0; j < 21; j++) d += at[t][j];
    dinv[t] = d > 0.f ? rsqrtf(d) : 0.f;
  }
  __syncthreads();
  if (t < 441) {
    int i = t / 21, j = t % 21;
    float a = dinv[i] * at[i][j] * dinv[j];
    Aout[t] = a > 0.1f ? a : 0.f;
  }
}

// ---------------- transpose f32 [K][N] -> f16 [N][K] ----------------
__global__ void k_transpose(const float* __restrict__ src, f16* __restrict__ dst,
                            int K, int N) {
  __shared__ float tile[32][33];
  int n0 = blockIdx.x * 32, k0 = blockIdx.y * 32;
  int tx = threadIdx.x, ty = threadIdx.y;   // (32,8)
  #pragma unroll
  for (int i = 0; i < 4; i++)
    tile[ty + 8*i][tx] = src[(size_t)(k0 + ty + 8*i) * N + n0 + tx];
  __syncthreads();
  #pragma unroll
  for (int i = 0; i < 4; i++)
    dst[(size_t)(n0 + ty + 8*i) * K + k0 + tx] = (f16)tile[tx][ty + 8*i];
}

// ---------------- node mean over 21 ----------------
__global__ void k_mean(const float* __restrict__ x, float* __restrict__ xm) {
  int b = blockIdx.x, t = threadIdx.x;
  for (int c = t; c < CIN; c += 256) {
    float s = 0.f;
    #pragma unroll
    for (int n = 0; n < NN; n++) s += x[((size_t)b*NN + n)*CIN + c];
    xm[(size_t)b*CIN + c] = s * (1.f/21.f);
  }
}

// ---------------- SE matmuls ----------------
__global__ void k_se1(const float* __restrict__ xm, const float* __restrict__ w1,
                      float* __restrict__ y1) {
  __shared__ float row[CIN];
  int b = blockIdx.x, t = threadIdx.x;   // 128 threads
  for (int k = t; k < CIN; k += 128) row[k] = xm[(size_t)b*CIN + k];
  __syncthreads();
  float acc = 0.f;
  for (int k = 0; k < CIN; k++) acc += row[k] * w1[(size_t)k*128 + t];
  y1[(size_t)b*128 + t] = fmaxf(acc, 0.f);
}

__global__ void k_se2(const float* __restrict__ y1, const float* __restrict__ w2,
                      float* __restrict__ y) {
  __shared__ float row[128];
  int b = blockIdx.x, t = threadIdx.x;   // 512 threads
  if (t < 128) row[t] = y1[(size_t)b*128 + t];
  __syncthreads();
  float acc = 0.f;
  for (int k = 0; k < 128; k++) acc += row[k] * w2[(size_t)k*CIN + t];
  y[(size_t)b*CIN + t] = 1.f / (1.f + expf(-acc));
}

// ---------------- gating: xg = f16(x * y[graph]) ----------------
__global__ void k_gate(const float* __restrict__ x, const float* __restrict__ y,
                       f16* __restrict__ xg) {
  size_t i8 = (size_t)blockIdx.x * 256 + threadIdx.x;
  size_t base = i8 * 8;
  int r = (int)(base >> 9);          // /512
  int c = (int)(base & 511);
  int b = r / 21;
  const float4* xp = (const float4*)(x + base);
  const float4* yp = (const float4*)(y + (size_t)b*CIN + c);
  float4 a0 = xp[0], a1 = xp[1];
  float4 g0 = yp[0], g1 = yp[1];
  f16x8 o;
  o[0] = (f16)(a0.x * g0.x); o[1] = (f16)(a0.y * g0.y);
  o[2] = (f16)(a0.z * g0.z); o[3] = (f16)(a0.w * g0.w);
  o[4] = (f16)(a1.x * g1.x); o[5] = (f16)(a1.y * g1.y);
  o[6] = (f16)(a1.z * g1.z); o[7] = (f16)(a1.w * g1.w);
  *(f16x8*)(xg + base) = o;
}

// ======== GEMM core (shared by all variants) ========
// 128x128 tile, BK=32, 4 waves. 1D grid, XCD-chunked swizzle, N-fastest tile
// order so the nbn N-siblings of each A-panel are temporally adjacent on one
// XCD's L2 (A fetched once instead of ~4-8x).
#define GEMM_PRE(A_, BT_, K_, lgn_)                                            \
  __shared__ __align__(16) f16 As[128*32];                                     \
  __shared__ __align__(16) f16 Bs[128*32];                                     \
  const int tid = threadIdx.x;                                                 \
  const int nwg = gridDim.x;                                                   \
  const int g = blockIdx.x;                                                    \
  const int swz = (g & 7) * (nwg >> 3) + (g >> 3);                             \
  const int bn = swz & ((1 << (lgn_)) - 1);                                    \
  const int bm = swz >> (lgn_);                                                \
  const int lane = tid & 63;                                                   \
  const int wr = (tid >> 7) & 1;                                               \
  const int wc = (tid >> 6) & 1;                                               \
  const int srow = tid >> 2;                                                   \
  const int scol = (tid & 3) << 3;                                             \
  const f16* Ag = (A_) + (size_t)(bm*128 + srow) * (K_) + scol;                \
  const f16* Bg = (BT_) + (size_t)(bn*128 + srow) * (K_) + scol;               \
  f16* AsP = As + tid * 8;                                                     \
  f16* BsP = Bs + tid * 8;                                                     \
  const size_t rstep = (size_t)64 * (K_);                                      \
  const int fr = lane & 15;                                                    \
  const int kg = (lane >> 4) << 3;                                             \
  const f16* ArP = As + (wr*64 + fr)*32 + kg;                                  \
  const f16* BrP = Bs + (wc*64 + fr)*32 + kg;                                  \
  f32x4 acc[4][4];                                                             \
  _Pragma("unroll") for (int m = 0; m < 4; m++)                                \
    _Pragma("unroll") for (int n = 0; n < 4; n++)                              \
      _Pragma("unroll") for (int r = 0; r < 4; r++) acc[m][n][r] = 0.f;        \
  for (int kt = 0; kt < (K_); kt += 32) {                                      \
    __builtin_amdgcn_global_load_lds((gas1)(Ag + kt),         (las3)AsP,           16, 0, 0); \
    __builtin_amdgcn_global_load_lds((gas1)(Ag + kt + rstep), (las3)(AsP + 64*32), 16, 0, 0); \
    __builtin_amdgcn_global_load_lds((gas1)(Bg + kt),         (las3)BsP,           16, 0, 0); \
    __builtin_amdgcn_global_load_lds((gas1)(Bg + kt + rstep), (las3)(BsP + 64*32), 16, 0, 0); \
    __syncthreads();                                                           \
    f16x8 af[4], bv[4];                                                        \
    _Pragma("unroll") for (int m = 0; m < 4; m++) af[m] = *(const f16x8*)(ArP + m*16*32); \
    _Pragma("unroll") for (int n = 0; n < 4; n++) bv[n] = *(const f16x8*)(BrP + n*16*32); \
    _Pragma("unroll") for (int m = 0; m < 4; m++)                              \
      _Pragma("unroll") for (int n = 0; n < 4; n++)                            \
        acc[m][n] = __builtin_amdgcn_mfma_f32_16x16x32_f16(af[m], bv[n], acc[m][n], 0, 0, 0); \
    __syncthreads();                                                           \
  }                                                                            \
  const int crow = bm*128 + wr*64 + ((lane >> 4) << 2);                        \
  const int ccol0 = bn*128 + wc*64 + fr;

// ---- f16-out GEMM ----
__global__ __launch_bounds__(256)
void k_gemm(const f16* __restrict__ A, const f16* __restrict__ BT,
            f16* __restrict__ C, int N, int K, int lgn) {
  GEMM_PRE(A, BT, K, lgn)
  #pragma unroll
  for (int m = 0; m < 4; m++)
    #pragma unroll
    for (int n = 0; n < 4; n++)
      #pragma unroll
      for (int r = 0; r < 4; r++)
        C[(size_t)(crow + m*16 + r) * N + (ccol0 + n*16)] = (f16)acc[m][n][r];
}

// ---- dual-output GEMM (layer 1: BT = [W1T;RS1T], N=2048, lgn=4) ----
__global__ __launch_bounds__(256)
void k_gemm2(const f16* __restrict__ A, const f16* __restrict__ BT,
             f16* __restrict__ C1, f16* __restrict__ C2, int K) {
  GEMM_PRE(A, BT, K, 4)
  f16* Cp = C1; int cc = ccol0;
  if (ccol0 >= 1024) { Cp = C2; cc = ccol0 - 1024; }
  #pragma unroll
  for (int m = 0; m < 4; m++)
    #pragma unroll
    for (int n = 0; n < 4; n++)
      #pragma unroll
      for (int r = 0; r < 4; r++)
        Cp[(size_t)(crow + m*16 + r) * 1024 + (cc + n*16)] = (f16)acc[m][n][r];
}

// ---- f32-out + bias GEMM (final fc) ----
__global__ __launch_bounds__(256)
void k_gemm_fc(const f16* __restrict__ A, const f16* __restrict__ BT,
               const float* __restrict__ bias, float* __restrict__ C,
               int N, int K, int lgn) {
  GEMM_PRE(A, BT, K, lgn)
  #pragma unroll
  for (int n = 0; n < 4; n++) {
    float bb = bias[ccol0 + n*16];
    #pragma unroll
    for (int m = 0; m < 4; m++)
      #pragma unroll
      for (int r = 0; r < 4; r++)
        C[(size_t)(crow + m*16 + r) * N + (ccol0 + n*16)] = acc[m][n][r] + bb;
  }
}

// ---------------- per-graph 21x21 mix, in-place + fused BN partial stats ----
__global__ __launch_bounds__(256)
void k_mix(f16* __restrict__ t, const float* __restrict__ Aadj,
           float* __restrict__ psum, float* __restrict__ psq, int C) {
  __shared__ float A[441];
  int b = blockIdx.x, tid = threadIdx.x;
  for (int i = tid; i < 441; i += 256) A[i] = Aadj[i];
  __syncthreads();
  size_t base = (size_t)b * NN * C;
  for (int c = tid; c < C; c += 256) {
    float v[21];
    #pragma unroll
    for (int j = 0; j < 21; j++) v[j] = (float)t[base + (size_t)j*C + c];
    float s = 0.f, q = 0.f;
    #pragma unroll
    for (int i = 0; i < 21; i++) {
      float acc = 0.f;
      #pragma unroll
      for (int j = 0; j < 21; j++) acc = fmaf(A[i*21 + j], v[j], acc);
      t[base + (size_t)i*C + c] = (f16)acc;
      s += acc; q += acc * acc;
    }
    psum[(size_t)b*C + c] = s;
    psq [(size_t)b*C + c] = q;
  }
}

// ---------------- reduce 4096 graph-partials -> 32 (deterministic) ----------
__global__ void k_reduce(const float* __restrict__ ps, const float* __restrict__ pq,
                         float* __restrict__ rs, float* __restrict__ rq, int C) {
  int c = blockIdx.x * 256 + threadIdx.x;
  int py = blockIdx.y;                 // 0..31
  float s = 0.f, q = 0.f;
  for (int p = py*128; p < py*128 + 128; p++) {
    s += ps[(size_t)p*C + c];
    q += pq[(size_t)p*C + c];
  }
  rs[(size_t)py*C + c] = s;
  rq[(size_t)py*C + c] = q;
}

__global__ void k_bnparams(const float* __restrict__ psum, const float* __restrict__ psq,
                           const float* __restrict__ gamma, const float* __restrict__ beta,
                           const float* __restrict__ resbias,
                           float* __restrict__ scale, float* __restrict__ shift,
                           int C, int npart) {
  int c = blockIdx.x * 256 + threadIdx.x;
  float s = 0.f, q = 0.f;
  for (int p = 0; p < npart; p++) { s += psum[(size_t)p*C + c]; q += psq[(size_t)p*C + c]; }
  const float Minv = 1.f / (float)MROWS;
  float mean = s * Minv;
  float var = q * Minv - mean * mean;
  float sc = gamma[c] * rsqrtf(var + 1e-5f);
  float sh = beta[c] - mean * sc;
  if (resbias) sh += resbias[c];
  scale[c] = sc; shift[c] = sh;
}

// ---------------- finalize: dst = relu(g*scale + shift + res) ----------------
__global__ void k_finalize(const f16* __restrict__ g, const f16* __restrict__ res,
                           f16* __restrict__ dst, const float* __restrict__ scale,
                           const float* __restrict__ shift, int cmask) {
  size_t i8 = (size_t)blockIdx.x * 256 + threadIdx.x;
  size_t base = i8 * 8;
  int c = (int)(base & (size_t)cmask);
  f16x8 gv = *(const f16x8*)(g + base);
  f16x8 rv = *(const f16x8*)(res + base);
  f16x8 o;
  #pragma unroll
  for (int j = 0; j < 8; j++) {
    float v = (float)gv[j] * scale[c + j] + shift[c + j] + (float)rv[j];
    o[j] = (f16)fmaxf(v, 0.f);
  }
  *(f16x8*)(dst + base) = o;
}

// ---------------- pool (mean over 21) + BN affine -> f16 ----------------
__global__ void k_pool(const f16* __restrict__ g3, const float* __restrict__ scale,
                       const float* __restrict__ shift, f16* __restrict__ pooled) {
  int b = blockIdx.x, t = threadIdx.x;
  for (int c = t; c < COUTC; c += 256) {
    float s = 0.f;
    #pragma unroll
    for (int n = 0; n < NN; n++) s += (float)g3[((size_t)b*NN + n)*COUTC + c];
    pooled[(size_t)b*COUTC + c] = (f16)((s * (1.f/21.f)) * scale[c] + shift[c]);
  }
}

extern "C" void kernel_launch(void* const* d_in, const int* in_sizes, int n_in,
                              void* d_out, int out_size, void* d_ws, size_t ws_size,
                              hipStream_t stream) {
  const float* x     = (const float*)d_in[0];
  const float* nv1   = (const float*)d_in[2];
  const float* nv2   = (const float*)d_in[3];
  const float* se_w1 = (const float*)d_in[4];
  const float* se_w2 = (const float*)d_in[5];
  const float* W1    = (const float*)d_in[6];
  const float* W2    = (const float*)d_in[8];
  const float* W3    = (const float*)d_in[10];
  const float* bn1g  = (const float*)d_in[12];
  const float* bn1b  = (const float*)d_in[13];
  const float* bn2g  = (const float*)d_in[14];
  const float* bn2b  = (const float*)d_in[15];
  const float* bn3g  = (const float*)d_in[16];
  const float* bn3b  = (const float*)d_in[17];
  const float* rs1w  = (const float*)d_in[18];
  const float* rs1b  = (const float*)d_in[19];
  const float* fcw   = (const float*)d_in[20];
  const float* fcb   = (const float*)d_in[21];
  float* out = (float*)d_out;

  char* ws = (char*)d_ws;
  size_t off = 0;
  auto alloc = [&](size_t bytes) -> char* {
    char* p = ws + off;
    off = (off + bytes + 255) & ~(size_t)255;
    return p;
  };

  float* A_adj = (float*)alloc(441 * 4);
  f16* W1R  = (f16*)alloc((size_t)2048 * CIN * 2);       // [W1T ; RS1T]
  f16* W2T  = (f16*)alloc((size_t)H2C * H1C * 2);
  f16* W3T  = (f16*)alloc((size_t)COUTC * H2C * 2);
  f16* FCWT = (f16*)alloc((size_t)1024 * COUTC * 2);
  float* xm = (float*)alloc((size_t)NB * CIN * 4);
  float* y1 = (float*)alloc((size_t)NB * 128 * 4);
  float* yv = (float*)alloc((size_t)NB * CIN * 4);
  float* psum = (float*)alloc((size_t)NB * 1024 * 4);    // per-graph partials
  float* psq  = (float*)alloc((size_t)NB * 1024 * 4);
  float* rsum = (float*)alloc((size_t)32 * 1024 * 4);
  float* rsq  = (float*)alloc((size_t)32 * 1024 * 4);
  float* sc1 = (float*)alloc(1024 * 4);
  float* sh1 = (float*)alloc(1024 * 4);
  float* sc2 = (float*)alloc(1024 * 4);
  float* sh2 = (float*)alloc(1024 * 4);
  float* sc3 = (float*)alloc(1024 * 4);
  float* sh3 = (float*)alloc(1024 * 4);
  f16* pooled = (f16*)alloc((size_t)NB * COUTC * 2);
  f16* P1 = (f16*)alloc((size_t)MROWS * 512 * 2);    // xg -> t3/g3
  f16* P2 = (f16*)alloc((size_t)MROWS * 1024 * 2);   // t1/g1 -> t2/g2 -> h2
  f16* P3 = (f16*)alloc((size_t)MROWS * 1024 * 2);   // r1 -> h1
  (void)ws_size; (void)in_sizes; (void)n_in; (void)out_size;

  // adjacency + weight transposes
  k_adj<<<1, 512, 0, stream>>>(nv1, nv2, A_adj);
  k_transpose<<<dim3(32, 16), dim3(32, 8), 0, stream>>>(W1,   W1R,                    512, 1024);
  k_transpose<<<dim3(32, 16), dim3(32, 8), 0, stream>>>(rs1w, W1R + (size_t)1024*512, 512, 1024);
  k_transpose<<<dim3(32, 32), dim3(32, 8), 0, stream>>>(W2,   W2T,  1024, 1024);
  k_transpose<<<dim3(16, 32), dim3(32, 8), 0, stream>>>(W3,   W3T,  1024, 512);
  k_transpose<<<dim3(32, 16), dim3(32, 8), 0, stream>>>(fcw,  FCWT, 512, 1024);

  // SE path
  k_mean<<<NB, 256, 0, stream>>>(x, xm);
  k_se1<<<NB, 128, 0, stream>>>(xm, se_w1, y1);
  k_se2<<<NB, 512, 0, stream>>>(y1, se_w2, yv);
  k_gate<<<21504, 256, 0, stream>>>(x, yv, P1);

  // layer 1: fused dual GEMM (t1 -> P2, r1 -> P3)
  k_gemm2<<<672*16, 256, 0, stream>>>(P1, W1R, P2, P3, 512);
  k_mix<<<NB, 256, 0, stream>>>(P2, A_adj, psum, psq, 1024);
  k_reduce<<<dim3(4, 32), 256, 0, stream>>>(psum, psq, rsum, rsq, 1024);
  k_bnparams<<<4, 256, 0, stream>>>(rsum, rsq, bn1g, bn1b, rs1b, sc1, sh1, 1024, 32);
  k_finalize<<<43008, 256, 0, stream>>>(P2, P3, P3, sc1, sh1, 1023);   // h1 -> P3

  // layer 2
  k_gemm<<<672*8, 256, 0, stream>>>(P3, W2T, P2, 1024, 1024, 3);
  k_mix<<<NB, 256, 0, stream>>>(P2, A_adj, psum, psq, 1024);
  k_reduce<<<dim3(4, 32), 256, 0, stream>>>(psum, psq, rsum, rsq, 1024);
  k_bnparams<<<4, 256, 0, stream>>>(rsum, rsq, bn2g, bn2b, nullptr, sc2, sh2, 1024, 32);
  k_finalize<<<43008, 256, 0, stream>>>(P2, P3, P2, sc2, sh2, 1023);   // h2 -> P2

  // layer 3
  k_gemm<<<672*4, 256, 0, stream>>>(P2, W3T, P1, 512, 1024, 2);
  k_mix<<<NB, 256, 0, stream>>>(P1, A_adj, psum, psq, 512);
  k_reduce<<<dim3(2, 32), 256, 0, stream>>>(psum, psq, rsum, rsq, 512);
  k_bnparams<<<2, 256, 0, stream>>>(rsum, rsq, bn3g, bn3b, nullptr, sc3, sh3, 512, 32);

  // pool + fc (MFMA)
  k_pool<<<NB, 256, 0, stream>>>(P1, sc3, sh3, pooled);
  k_gemm_fc<<<32*8, 256, 0, stream>>>(pooled, FCWT, fcb, out, 1024, COUTC, 3);
}

// Round 5
// 1317.227 us; speedup vs baseline: 3.8891x; 1.4484x over previous
//
#include <hip/hip_runtime.h>

typedef _Float16 f16;
typedef f16 f16x2 __attribute__((ext_vector_type(2)));
typedef f16 f16x8 __attribute__((ext_vector_type(8)));
typedef float f32x4 __attribute__((ext_vector_type(4)));
typedef const void __attribute__((address_space(1)))* gas1;
typedef void __attribute__((address_space(3)))* las3;

#define NB 4096
#define NN 21
#define MROWS (NB*NN)      // 86016
#define CIN 512
#define H1C 1024
#define H2C 1024
#define COUTC 512

// ---------------- adjacency ----------------
__global__ void k_adj(const float* __restrict__ nv1, const float* __restrict__ nv2,
                      float* __restrict__ Aout) {
  __shared__ float at[21][21];
  __shared__ float dinv[21];
  int t = threadIdx.x;
  if (t < 441) {
    int i = t / 21, j = t % 21;
    float s = 0.f;
    #pragma unroll
    for (int r = 0; r < 10; r++) s += nv1[i*10 + r] * nv2[r*21 + j];
    float v = 1.f / (1.f + expf(-s));
    if (i == j) v += 1.f;
    at[i][j] = v;
  }
  __syncthreads();
  if (t < 21) {
    float d = 0.f;
    #pragma unroll
    for (int j = 0; j < 21; j++) d += at[t][j];
    dinv[t] = d > 0.f ? rsqrtf(d) : 0.f;
  }
  __syncthreads();
  if (t < 441) {
    int i = t / 21, j = t % 21;
    float a = dinv[i] * at[i][j] * dinv[j];
    Aout[t] = a > 0.1f ? a : 0.f;
  }
}

// ---------------- transpose f32 [K][N] -> f16 [N][K] ----------------
__global__ void k_transpose(const float* __restrict__ src, f16* __restrict__ dst,
                            int K, int N) {
  __shared__ float tile[32][33];
  int n0 = blockIdx.x * 32, k0 = blockIdx.y * 32;
  int tx = threadIdx.x, ty = threadIdx.y;   // (32,8)
  #pragma unroll
  for (int i = 0; i < 4; i++)
    tile[ty + 8*i][tx] = src[(size_t)(k0 + ty + 8*i) * N + n0 + tx];
  __syncthreads();
  #pragma unroll
  for (int i = 0; i < 4; i++)
    dst[(size_t)(n0 + ty + 8*i) * K + k0 + tx] = (f16)tile[tx][ty + 8*i];
}

// ---------------- node mean over 21 ----------------
__global__ void k_mean(const float* __restrict__ x, float* __restrict__ xm) {
  int b = blockIdx.x, t = threadIdx.x;
  for (int c = t; c < CIN; c += 256) {
    float s = 0.f;
    #pragma unroll
    for (int n = 0; n < NN; n++) s += x[((size_t)b*NN + n)*CIN + c];
    xm[(size_t)b*CIN + c] = s * (1.f/21.f);
  }
}

// ---------------- SE matmuls ----------------
__global__ void k_se1(const float* __restrict__ xm, const float* __restrict__ w1,
                      float* __restrict__ y1) {
  __shared__ float row[CIN];
  int b = blockIdx.x, t = threadIdx.x;   // 128 threads
  for (int k = t; k < CIN; k += 128) row[k] = xm[(size_t)b*CIN + k];
  __syncthreads();
  float acc = 0.f;
  for (int k = 0; k < CIN; k++) acc += row[k] * w1[(size_t)k*128 + t];
  y1[(size_t)b*128 + t] = fmaxf(acc, 0.f);
}

__global__ void k_se2(const float* __restrict__ y1, const float* __restrict__ w2,
                      float* __restrict__ y) {
  __shared__ float row[128];
  int b = blockIdx.x, t = threadIdx.x;   // 512 threads
  if (t < 128) row[t] = y1[(size_t)b*128 + t];
  __syncthreads();
  float acc = 0.f;
  for (int k = 0; k < 128; k++) acc += row[k] * w2[(size_t)k*CIN + t];
  y[(size_t)b*CIN + t] = 1.f / (1.f + expf(-acc));
}

// ---------------- gating: xg = f16(x * y[graph]) ----------------
__global__ void k_gate(const float* __restrict__ x, const float* __restrict__ y,
                       f16* __restrict__ xg) {
  size_t i8 = (size_t)blockIdx.x * 256 + threadIdx.x;
  size_t base = i8 * 8;
  int r = (int)(base >> 9);          // /512
  int c = (int)(base & 511);
  int b = r / 21;
  const float4* xp = (const float4*)(x + base);
  const float4* yp = (const float4*)(y + (size_t)b*CIN + c);
  float4 a0 = xp[0], a1 = xp[1];
  float4 g0 = yp[0], g1 = yp[1];
  f16x8 o;
  o[0] = (f16)(a0.x * g0.x); o[1] = (f16)(a0.y * g0.y);
  o[2] = (f16)(a0.z * g0.z); o[3] = (f16)(a0.w * g0.w);
  o[4] = (f16)(a1.x * g1.x); o[5] = (f16)(a1.y * g1.y);
  o[6] = (f16)(a1.z * g1.z); o[7] = (f16)(a1.w * g1.w);
  *(f16x8*)(xg + base) = o;
}

// ======== GEMM core (shared by all variants) ========
// 128x128 tile, BK=32, 4 waves. 1D grid, XCD-chunked swizzle, N-fastest tile
// order so the N-siblings of each A-panel are temporally adjacent on one
// XCD's L2 (A fetched once instead of ~4-8x).
#define GEMM_PRE(A_, BT_, K_, lgn_)                                            \
  __shared__ __align__(16) f16 As[128*32];                                     \
  __shared__ __align__(16) f16 Bs[128*32];                                     \
  const int tid = threadIdx.x;                                                 \
  const int nwg = gridDim.x;                                                   \
  const int g = blockIdx.x;                                                    \
  const int swz = (g & 7) * (nwg >> 3) + (g >> 3);                             \
  const int bn = swz & ((1 << (lgn_)) - 1);                                    \
  const int bm = swz >> (lgn_);                                                \
  const int lane = tid & 63;                                                   \
  const int wr = (tid >> 7) & 1;                                               \
  const int wc = (tid >> 6) & 1;                                               \
  const int srow = tid >> 2;                                                   \
  const int scol = (tid & 3) << 3;                                             \
  const f16* Ag = (A_) + (size_t)(bm*128 + srow) * (K_) + scol;                \
  const f16* Bg = (BT_) + (size_t)(bn*128 + srow) * (K_) + scol;               \
  f16* AsP = As + tid * 8;                                                     \
  f16* BsP = Bs + tid * 8;                                                     \
  const size_t rstep = (size_t)64 * (K_);                                      \
  const int fr = lane & 15;                                                    \
  const int kg = (lane >> 4) << 3;                                             \
  const f16* ArP = As + (wr*64 + fr)*32 + kg;                                  \
  const f16* BrP = Bs + (wc*64 + fr)*32 + kg;                                  \
  f32x4 acc[4][4];                                                             \
  _Pragma("unroll") for (int m = 0; m < 4; m++)                                \
    _Pragma("unroll") for (int n = 0; n < 4; n++)                              \
      _Pragma("unroll") for (int r = 0; r < 4; r++) acc[m][n][r] = 0.f;        \
  for (int kt = 0; kt < (K_); kt += 32) {                                      \
    __builtin_amdgcn_global_load_lds((gas1)(Ag + kt),         (las3)AsP,           16, 0, 0); \
    __builtin_amdgcn_global_load_lds((gas1)(Ag + kt + rstep), (las3)(AsP + 64*32), 16, 0, 0); \
    __builtin_amdgcn_global_load_lds((gas1)(Bg + kt),         (las3)BsP,           16, 0, 0); \
    __builtin_amdgcn_global_load_lds((gas1)(Bg + kt + rstep), (las3)(BsP + 64*32), 16, 0, 0); \
    __syncthreads();                                                           \
    f16x8 af[4], bv[4];                                                        \
    _Pragma("unroll") for (int m = 0; m < 4; m++) af[m] = *(const f16x8*)(ArP + m*16*32); \
    _Pragma("unroll") for (int n = 0; n < 4; n++) bv[n] = *(const f16x8*)(BrP + n*16*32); \
    _Pragma("unroll") for (int m = 0; m < 4; m++)                              \
      _Pragma("unroll") for (int n = 0; n < 4; n++)                            \
        acc[m][n] = __builtin_amdgcn_mfma_f32_16x16x32_f16(af[m], bv[n], acc[m][n], 0, 0, 0); \
    __syncthreads();                                                           \
  }                                                                            \
  const int crow = bm*128 + wr*64 + ((lane >> 4) << 2);                        \
  const int ccol0 = bn*128 + wc*64 + fr;

// ---- f16-out GEMM ----
__global__ __launch_bounds__(256)
void k_gemm(const f16* __restrict__ A, const f16* __restrict__ BT,
            f16* __restrict__ C, int N, int K, int lgn) {
  GEMM_PRE(A, BT, K, lgn)
  #pragma unroll
  for (int m = 0; m < 4; m++)
    #pragma unroll
    for (int n = 0; n < 4; n++)
      #pragma unroll
      for (int r = 0; r < 4; r++)
        C[(size_t)(crow + m*16 + r) * N + (ccol0 + n*16)] = (f16)acc[m][n][r];
}

// ---- dual-output GEMM (layer 1: BT = [W1T;RS1T], N=2048, lgn=4) ----
__global__ __launch_bounds__(256)
void k_gemm2(const f16* __restrict__ A, const f16* __restrict__ BT,
             f16* __restrict__ C1, f16* __restrict__ C2, int K) {
  GEMM_PRE(A, BT, K, 4)
  f16* Cp = C1; int cc = ccol0;
  if (ccol0 >= 1024) { Cp = C2; cc = ccol0 - 1024; }
  #pragma unroll
  for (int m = 0; m < 4; m++)
    #pragma unroll
    for (int n = 0; n < 4; n++)
      #pragma unroll
      for (int r = 0; r < 4; r++)
        Cp[(size_t)(crow + m*16 + r) * 1024 + (cc + n*16)] = (f16)acc[m][n][r];
}

// ---- f32-out + bias GEMM (final fc) ----
__global__ __launch_bounds__(256)
void k_gemm_fc(const f16* __restrict__ A, const f16* __restrict__ BT,
               const float* __restrict__ bias, float* __restrict__ C,
               int N, int K, int lgn) {
  GEMM_PRE(A, BT, K, lgn)
  #pragma unroll
  for (int n = 0; n < 4; n++) {
    float bb = bias[ccol0 + n*16];
    #pragma unroll
    for (int m = 0; m < 4; m++)
      #pragma unroll
      for (int r = 0; r < 4; r++)
        C[(size_t)(crow + m*16 + r) * N + (ccol0 + n*16)] = acc[m][n][r] + bb;
  }
}

// ---------------- per-graph 21x21 mix + fused BN partial stats --------------
// One f16x2 channel-pair per thread, NO outer loop: 42 live floats -> ~70 VGPR
// (round-4 version looped over channels; pipelining blew VGPR to 244,
//  occupancy 11%, latency-bound at 0.9 TB/s).
// grid = (NB, C/512), block = 256.
__global__ __launch_bounds__(256)
void k_mix(f16* __restrict__ t, const float* __restrict__ Aadj,
           float* __restrict__ psum, float* __restrict__ psq, int C) {
  __shared__ float A[441];
  int b = blockIdx.x, tid = threadIdx.x;
  for (int i = tid; i < 441; i += 256) A[i] = Aadj[i];
  __syncthreads();
  int c0 = (blockIdx.y * 256 + tid) * 2;
  size_t base = (size_t)b * NN * C + c0;
  float vx[21], vy[21];
  #pragma unroll
  for (int j = 0; j < 21; j++) {
    f16x2 v = *(const f16x2*)(t + base + (size_t)j * C);
    vx[j] = (float)v[0]; vy[j] = (float)v[1];
  }
  float s0 = 0.f, s1 = 0.f, q0 = 0.f, q1 = 0.f;
  #pragma unroll
  for (int i = 0; i < 21; i++) {
    float a0 = 0.f, a1 = 0.f;
    #pragma unroll
    for (int j = 0; j < 21; j++) {
      float w = A[i*21 + j];
      a0 = fmaf(w, vx[j], a0);
      a1 = fmaf(w, vy[j], a1);
    }
    f16x2 o; o[0] = (f16)a0; o[1] = (f16)a1;
    *(f16x2*)(t + base + (size_t)i * C) = o;
    s0 += a0; s1 += a1;
    q0 = fmaf(a0, a0, q0); q1 = fmaf(a1, a1, q1);
  }
  float2 sv; sv.x = s0; sv.y = s1;
  float2 qv; qv.x = q0; qv.y = q1;
  *(float2*)(psum + (size_t)b * C + c0) = sv;
  *(float2*)(psq  + (size_t)b * C + c0) = qv;
}

// ---------------- reduce 4096 graph-partials -> 32 (deterministic) ----------
__global__ void k_reduce(const float* __restrict__ ps, const float* __restrict__ pq,
                         float* __restrict__ rs, float* __restrict__ rq, int C) {
  int c = blockIdx.x * 256 + threadIdx.x;
  int py = blockIdx.y;                 // 0..31
  float s = 0.f, q = 0.f;
  for (int p = py*128; p < py*128 + 128; p++) {
    s += ps[(size_t)p*C + c];
    q += pq[(size_t)p*C + c];
  }
  rs[(size_t)py*C + c] = s;
  rq[(size_t)py*C + c] = q;
}

__global__ void k_bnparams(const float* __restrict__ psum, const float* __restrict__ psq,
                           const float* __restrict__ gamma, const float* __restrict__ beta,
                           const float* __restrict__ resbias,
                           float* __restrict__ scale, float* __restrict__ shift,
                           int C, int npart) {
  int c = blockIdx.x * 256 + threadIdx.x;
  float s = 0.f, q = 0.f;
  for (int p = 0; p < npart; p++) { s += psum[(size_t)p*C + c]; q += psq[(size_t)p*C + c]; }
  const float Minv = 1.f / (float)MROWS;
  float mean = s * Minv;
  float var = q * Minv - mean * mean;
  float sc = gamma[c] * rsqrtf(var + 1e-5f);
  float sh = beta[c] - mean * sc;
  if (resbias) sh += resbias[c];
  scale[c] = sc; shift[c] = sh;
}

// ---------------- finalize: dst = relu(g*scale + shift + res) ----------------
__global__ void k_finalize(const f16* __restrict__ g, const f16* __restrict__ res,
                           f16* __restrict__ dst, const float* __restrict__ scale,
                           const float* __restrict__ shift, int cmask) {
  size_t i8 = (size_t)blockIdx.x * 256 + threadIdx.x;
  size_t base = i8 * 8;
  int c = (int)(base & (size_t)cmask);
  f16x8 gv = *(const f16x8*)(g + base);
  f16x8 rv = *(const f16x8*)(res + base);
  f16x8 o;
  #pragma unroll
  for (int j = 0; j < 8; j++) {
    float v = (float)gv[j] * scale[c + j] + shift[c + j] + (float)rv[j];
    o[j] = (f16)fmaxf(v, 0.f);
  }
  *(f16x8*)(dst + base) = o;
}

// ---------------- pool (mean over 21) + BN affine -> f16 ----------------
__global__ void k_pool(const f16* __restrict__ g3, const float* __restrict__ scale,
                       const float* __restrict__ shift, f16* __restrict__ pooled) {
  int b = blockIdx.x, t = threadIdx.x;
  for (int c = t; c < COUTC; c += 256) {
    float s = 0.f;
    #pragma unroll
    for (int n = 0; n < NN; n++) s += (float)g3[((size_t)b*NN + n)*COUTC + c];
    pooled[(size_t)b*COUTC + c] = (f16)((s * (1.f/21.f)) * scale[c] + shift[c]);
  }
}

extern "C" void kernel_launch(void* const* d_in, const int* in_sizes, int n_in,
                              void* d_out, int out_size, void* d_ws, size_t ws_size,
                              hipStream_t stream) {
  const float* x     = (const float*)d_in[0];
  const float* nv1   = (const float*)d_in[2];
  const float* nv2   = (const float*)d_in[3];
  const float* se_w1 = (const float*)d_in[4];
  const float* se_w2 = (const float*)d_in[5];
  const float* W1    = (const float*)d_in[6];
  const float* W2    = (const float*)d_in[8];
  const float* W3    = (const float*)d_in[10];
  const float* bn1g  = (const float*)d_in[12];
  const float* bn1b  = (const float*)d_in[13];
  const float* bn2g  = (const float*)d_in[14];
  const float* bn2b  = (const float*)d_in[15];
  const float* bn3g  = (const float*)d_in[16];
  const float* bn3b  = (const float*)d_in[17];
  const float* rs1w  = (const float*)d_in[18];
  const float* rs1b  = (const float*)d_in[19];
  const float* fcw   = (const float*)d_in[20];
  const float* fcb   = (const float*)d_in[21];
  float* out = (float*)d_out;

  char* ws = (char*)d_ws;
  size_t off = 0;
  auto alloc = [&](size_t bytes) -> char* {
    char* p = ws + off;
    off = (off + bytes + 255) & ~(size_t)255;
    return p;
  };

  float* A_adj = (float*)alloc(441 * 4);
  f16* W1R  = (f16*)alloc((size_t)2048 * CIN * 2);       // [W1T ; RS1T]
  f16* W2T  = (f16*)alloc((size_t)H2C * H1C * 2);
  f16* W3T  = (f16*)alloc((size_t)COUTC * H2C * 2);
  f16* FCWT = (f16*)alloc((size_t)1024 * COUTC * 2);
  float* xm = (float*)alloc((size_t)NB * CIN * 4);
  float* y1 = (float*)alloc((size_t)NB * 128 * 4);
  float* yv = (float*)alloc((size_t)NB * CIN * 4);
  float* psum = (float*)alloc((size_t)NB * 1024 * 4);    // per-graph partials
  float* psq  = (float*)alloc((size_t)NB * 1024 * 4);
  float* rsum = (float*)alloc((size_t)32 * 1024 * 4);
  float* rsq  = (float*)alloc((size_t)32 * 1024 * 4);
  float* sc1 = (float*)alloc(1024 * 4);
  float* sh1 = (float*)alloc(1024 * 4);
  float* sc2 = (float*)alloc(1024 * 4);
  float* sh2 = (float*)alloc(1024 * 4);
  float* sc3 = (float*)alloc(1024 * 4);
  float* sh3 = (float*)alloc(1024 * 4);
  f16* pooled = (f16*)alloc((size_t)NB * COUTC * 2);
  f16* P1 = (f16*)alloc((size_t)MROWS * 512 * 2);    // xg -> t3/g3
  f16* P2 = (f16*)alloc((size_t)MROWS * 1024 * 2);   // t1/g1 -> t2/g2 -> h2
  f16* P3 = (f16*)alloc((size_t)MROWS * 1024 * 2);   // r1 -> h1
  (void)ws_size; (void)in_sizes; (void)n_in; (void)out_size;

  // adjacency + weight transposes
  k_adj<<<1, 512, 0, stream>>>(nv1, nv2, A_adj);
  k_transpose<<<dim3(32, 16), dim3(32, 8), 0, stream>>>(W1,   W1R,                    512, 1024);
  k_transpose<<<dim3(32, 16), dim3(32, 8), 0, stream>>>(rs1w, W1R + (size_t)1024*512, 512, 1024);
  k_transpose<<<dim3(32, 32), dim3(32, 8), 0, stream>>>(W2,   W2T,  1024, 1024);
  k_transpose<<<dim3(16, 32), dim3(32, 8), 0, stream>>>(W3,   W3T,  1024, 512);
  k_transpose<<<dim3(32, 16), dim3(32, 8), 0, stream>>>(fcw,  FCWT, 512, 1024);

  // SE path
  k_mean<<<NB, 256, 0, stream>>>(x, xm);
  k_se1<<<NB, 128, 0, stream>>>(xm, se_w1, y1);
  k_se2<<<NB, 512, 0, stream>>>(y1, se_w2, yv);
  k_gate<<<21504, 256, 0, stream>>>(x, yv, P1);

  // layer 1: fused dual GEMM (t1 -> P2, r1 -> P3)
  k_gemm2<<<672*16, 256, 0, stream>>>(P1, W1R, P2, P3, 512);
  k_mix<<<dim3(NB, 2), 256, 0, stream>>>(P2, A_adj, psum, psq, 1024);
  k_reduce<<<dim3(4, 32), 256, 0, stream>>>(psum, psq, rsum, rsq, 1024);
  k_bnparams<<<4, 256, 0, stream>>>(rsum, rsq, bn1g, bn1b, rs1b, sc1, sh1, 1024, 32);
  k_finalize<<<43008, 256, 0, stream>>>(P2, P3, P3, sc1, sh1, 1023);   // h1 -> P3

  // layer 2
  k_gemm<<<672*8, 256, 0, stream>>>(P3, W2T, P2, 1024, 1024, 3);
  k_mix<<<dim3(NB, 2), 256, 0, stream>>>(P2, A_adj, psum, psq, 1024);
  k_reduce<<<dim3(4, 32), 256, 0, stream>>>(psum, psq, rsum, rsq, 1024);
  k_bnparams<<<4, 256, 0, stream>>>(rsum, rsq, bn2g, bn2b, nullptr, sc2, sh2, 1024, 32);
  k_finalize<<<43008, 256, 0, stream>>>(P2, P3, P2, sc2, sh2, 1023);   // h2 -> P2

  // layer 3
  k_gemm<<<672*4, 256, 0, stream>>>(P2, W3T, P1, 512, 1024, 2);
  k_mix<<<dim3(NB, 1), 256, 0, stream>>>(P1, A_adj, psum, psq, 512);
  k_reduce<<<dim3(2, 32), 256, 0, stream>>>(psum, psq, rsum, rsq, 512);
  k_bnparams<<<2, 256, 0, stream>>>(rsum, rsq, bn3g, bn3b, nullptr, sc3, sh3, 512, 32);

  // pool + fc (MFMA)
  k_pool<<<NB, 256, 0, stream>>>(P1, sc3, sh3, pooled);
  k_gemm_fc<<<32*8, 256, 0, stream>>>(pooled, FCWT, fcb, out, 1024, COUTC, 3);
}

// Round 6
// 1215.135 us; speedup vs baseline: 4.2158x; 1.0840x over previous
//
#include <hip/hip_runtime.h>

typedef _Float16 f16;
typedef f16 f16x2 __attribute__((ext_vector_type(2)));
typedef f16 f16x8 __attribute__((ext_vector_type(8)));
typedef float f32x4 __attribute__((ext_vector_type(4)));
typedef const void __attribute__((address_space(1)))* gas1;
typedef void __attribute__((address_space(3)))* las3;

#define NB 4096
#define NN 21
#define MROWS (NB*NN)      // 86016
#define CIN 512
#define H1C 1024
#define H2C 1024
#define COUTC 512

// ---------------- adjacency ----------------
__global__ void k_adj(const float* __restrict__ nv1, const float* __restrict__ nv2,
                      float* __restrict__ Aout) {
  __shared__ float at[21][21];
  __shared__ float dinv[21];
  int t = threadIdx.x;
  if (t < 441) {
    int i = t / 21, j = t % 21;
    float s = 0.f;
    #pragma unroll
    for (int r = 0; r < 10; r++) s += nv1[i*10 + r] * nv2[r*21 + j];
    float v = 1.f / (1.f + expf(-s));
    if (i == j) v += 1.f;
    at[i][j] = v;
  }
  __syncthreads();
  if (t < 21) {
    float d = 0.f;
    #pragma unroll
    for (int j = 0; j < 21; j++) d += at[t][j];
    dinv[t] = d > 0.f ? rsqrtf(d) : 0.f;
  }
  __syncthreads();
  if (t < 441) {
    int i = t / 21, j = t % 21;
    float a = dinv[i] * at[i][j] * dinv[j];
    Aout[t] = a > 0.1f ? a : 0.f;
  }
}

// ---------------- transpose f32 [K][N] -> f16 [N][K] ----------------
__global__ void k_transpose(const float* __restrict__ src, f16* __restrict__ dst,
                            int K, int N) {
  __shared__ float tile[32][33];
  int n0 = blockIdx.x * 32, k0 = blockIdx.y * 32;
  int tx = threadIdx.x, ty = threadIdx.y;   // (32,8)
  #pragma unroll
  for (int i = 0; i < 4; i++)
    tile[ty + 8*i][tx] = src[(size_t)(k0 + ty + 8*i) * N + n0 + tx];
  __syncthreads();
  #pragma unroll
  for (int i = 0; i < 4; i++)
    dst[(size_t)(n0 + ty + 8*i) * K + k0 + tx] = (f16)tile[tx][ty + 8*i];
}

// ---------------- node mean over 21 ----------------
__global__ void k_mean(const float* __restrict__ x, float* __restrict__ xm) {
  int b = blockIdx.x, t = threadIdx.x;
  for (int c = t; c < CIN; c += 256) {
    float s = 0.f;
    #pragma unroll
    for (int n = 0; n < NN; n++) s += x[((size_t)b*NN + n)*CIN + c];
    xm[(size_t)b*CIN + c] = s * (1.f/21.f);
  }
}

// ---------------- SE matmuls ----------------
__global__ void k_se1(const float* __restrict__ xm, const float* __restrict__ w1,
                      float* __restrict__ y1) {
  __shared__ float row[CIN];
  int b = blockIdx.x, t = threadIdx.x;   // 128 threads
  for (int k = t; k < CIN; k += 128) row[k] = xm[(size_t)b*CIN + k];
  __syncthreads();
  float acc = 0.f;
  for (int k = 0; k < CIN; k++) acc += row[k] * w1[(size_t)k*128 + t];
  y1[(size_t)b*128 + t] = fmaxf(acc, 0.f);
}

__global__ void k_se2(const float* __restrict__ y1, const float* __restrict__ w2,
                      float* __restrict__ y) {
  __shared__ float row[128];
  int b = blockIdx.x, t = threadIdx.x;   // 512 threads
  if (t < 128) row[t] = y1[(size_t)b*128 + t];
  __syncthreads();
  float acc = 0.f;
  for (int k = 0; k < 128; k++) acc += row[k] * w2[(size_t)k*CIN + t];
  y[(size_t)b*CIN + t] = 1.f / (1.f + expf(-acc));
}

// ---------------- gating: xg = f16(x * y[graph]) ----------------
__global__ void k_gate(const float* __restrict__ x, const float* __restrict__ y,
                       f16* __restrict__ xg) {
  size_t i8 = (size_t)blockIdx.x * 256 + threadIdx.x;
  size_t base = i8 * 8;
  int r = (int)(base >> 9);          // /512
  int c = (int)(base & 511);
  int b = r / 21;
  const float4* xp = (const float4*)(x + base);
  const float4* yp = (const float4*)(y + (size_t)b*CIN + c);
  float4 a0 = xp[0], a1 = xp[1];
  float4 g0 = yp[0], g1 = yp[1];
  f16x8 o;
  o[0] = (f16)(a0.x * g0.x); o[1] = (f16)(a0.y * g0.y);
  o[2] = (f16)(a0.z * g0.z); o[3] = (f16)(a0.w * g0.w);
  o[4] = (f16)(a1.x * g1.x); o[5] = (f16)(a1.y * g1.y);
  o[6] = (f16)(a1.z * g1.z); o[7] = (f16)(a1.w * g1.w);
  *(f16x8*)(xg + base) = o;
}

// ======== 8-wave phased GEMM: C[M][N] = A[M][K] @ BT[N][K]^T ========
// BM=128, BN=256, BK=64; 512 threads = 8 waves (2M x 4N), per-wave 64x64 out.
// Triple-buffered LDS (3 x 48KB): tile t read from buf[t%3] while tile t+2
// stages into buf[(t+2)%3] (never concurrently read -> race-free), enabling
// counted vmcnt(6) (= 1 tile / 6 loads in flight) instead of a vmcnt(0) drain.
// T2: granule-XOR swizzle (g ^= row&7) on global source + ds_read (gload_lds
// dest stays linear). T5: setprio around the MFMA cluster.
// MODE 0: f16 out (stride N). MODE 1: dual f16 out, cols<1024 -> C1 else C2
// (both stride 1024). MODE 2: f32 out + bias.
#define GBM 128
#define GBN 256
#define BUFB 49152            // A: 128*64*2 = 16384 B, B: 256*64*2 = 32768 B

template<int MODE>
__global__ __launch_bounds__(512, 1)
void k_gemm8(const f16* __restrict__ A, const f16* __restrict__ BT,
             f16* __restrict__ C1, f16* __restrict__ C2,
             const float* __restrict__ bias, float* __restrict__ Cf,
             int N, int K, int lgn) {
  __shared__ __align__(16) char lds[3 * BUFB];
  const int tid = threadIdx.x;
  const int nwg = gridDim.x;
  const int g = blockIdx.x;
  const int swz = (g & 7) * (nwg >> 3) + (g >> 3);   // XCD-chunked, nwg%8==0
  const int bn = swz & ((1 << lgn) - 1);             // N fastest: A-panel L2 reuse
  const int bm = swz >> lgn;
  const int lane = tid & 63;
  const int wid = tid >> 6;
  const int wr = wid >> 2;          // 0..1
  const int wc = wid & 3;           // 0..3
  const int fr = lane & 15;
  const int kg = lane >> 4;         // 0..3

  // staging map: 6 x 16B granules per thread per K-tile (A: j=0..1, B: j=2..5)
  size_t srcOff[6]; int ldsOff[6];
  #pragma unroll
  for (int j = 0; j < 6; j++) {
    int gid = j * 512 + tid;
    if (gid < 1024) {               // A: 128 rows x 8 granules
      int row = gid >> 3, gr = gid & 7;
      int gsw = gr ^ (row & 7);     // pre-swizzled source granule
      srcOff[j] = (size_t)(bm * GBM + row) * K + gsw * 8;
      ldsOff[j] = gid * 16;         // linear dest (gload_lds requirement)
    } else {                        // B: 256 rows x 8 granules
      int bgid = gid - 1024;
      int row = bgid >> 3, gr = bgid & 7;
      int gsw = gr ^ (row & 7);
      srcOff[j] = (size_t)(bn * GBN + row) * K + gsw * 8;
      ldsOff[j] = 16384 + bgid * 16;
    }
  }

  // fragment read bases (byte) + per-row swizzle keys
  int aOff[4], axor[4], bOff[4], bxor[4];
  #pragma unroll
  for (int m = 0; m < 4; m++) {
    int row = wr*64 + m*16 + fr;
    aOff[m] = row * 128; axor[m] = row & 7;
  }
  #pragma unroll
  for (int n = 0; n < 4; n++) {
    int row = wc*64 + n*16 + fr;
    bOff[n] = 16384 + row * 128; bxor[n] = row & 7;
  }

  f32x4 acc[4][4];
  #pragma unroll
  for (int m = 0; m < 4; m++)
    #pragma unroll
    for (int n = 0; n < 4; n++)
      #pragma unroll
      for (int r = 0; r < 4; r++) acc[m][n][r] = 0.f;

  auto STAGE3 = [&](int t2, int sbuf, int j0) {
    char* dst = (char*)lds + sbuf * BUFB;
    const size_t kof = (size_t)t2 * 64;
    #pragma unroll
    for (int j = 0; j < 3; j++) {
      int jj = j0 + j;
      const f16* src = (jj < 2 ? A : BT) + srcOff[jj] + kof;
      __builtin_amdgcn_global_load_lds((gas1)src, (las3)(dst + ldsOff[jj]), 16, 0, 0);
    }
  };

  const int NT = K >> 6;
  // prologue: stage tiles 0,1; wait tile 0 (6 of tile 1 stay in flight)
  STAGE3(0, 0, 0); STAGE3(0, 0, 3);
  STAGE3(1, 1, 0); STAGE3(1, 1, 3);
  asm volatile("s_waitcnt vmcnt(6)" ::: "memory");
  asm volatile("s_barrier" ::: "memory");

  for (int t = 0; t < NT; t++) {
    const int cb = t % 3;
    const int sb = (t + 2) % 3;
    const char* rb = (const char*)lds + cb * BUFB;
    const bool ds = (t + 2) < NT;

    // ---- phase 0 (k-slice 0) ----
    f16x8 av[4], bv[4];
    #pragma unroll
    for (int m = 0; m < 4; m++)
      av[m] = *(const f16x8*)(rb + aOff[m] + ((kg ^ axor[m]) << 4));
    #pragma unroll
    for (int n = 0; n < 4; n++)
      bv[n] = *(const f16x8*)(rb + bOff[n] + ((kg ^ bxor[n]) << 4));
    if (ds) STAGE3(t + 2, sb, 0);
    asm volatile("s_barrier" ::: "memory");
    __builtin_amdgcn_s_setprio(1);
    #pragma unroll
    for (int m = 0; m < 4; m++)
      #pragma unroll
      for (int n = 0; n < 4; n++)
        acc[m][n] = __builtin_amdgcn_mfma_f32_16x16x32_f16(av[m], bv[n], acc[m][n], 0, 0, 0);
    __builtin_amdgcn_s_setprio(0);
    asm volatile("s_barrier" ::: "memory");

    // ---- phase 1 (k-slice 1) ----
    #pragma unroll
    for (int m = 0; m < 4; m++)
      av[m] = *(const f16x8*)(rb + aOff[m] + (((4 + kg) ^ axor[m]) << 4));
    #pragma unroll
    for (int n = 0; n < 4; n++)
      bv[n] = *(const f16x8*)(rb + bOff[n] + (((4 + kg) ^ bxor[n]) << 4));
    if (ds) STAGE3(t + 2, sb, 3);
    asm volatile("s_barrier" ::: "memory");
    __builtin_amdgcn_s_setprio(1);
    #pragma unroll
    for (int m = 0; m < 4; m++)
      #pragma unroll
      for (int n = 0; n < 4; n++)
        acc[m][n] = __builtin_amdgcn_mfma_f32_16x16x32_f16(av[m], bv[n], acc[m][n], 0, 0, 0);
    __builtin_amdgcn_s_setprio(0);
    // counted wait: ensure tile t+1 landed; tile t+2's 6 loads stay in flight
    if (ds) asm volatile("s_waitcnt vmcnt(6)" ::: "memory");
    else    asm volatile("s_waitcnt vmcnt(0)" ::: "memory");
    asm volatile("s_barrier" ::: "memory");
  }

  const int crow = bm * GBM + wr * 64 + ((lane >> 4) << 2);
  const int ccol = bn * GBN + wc * 64 + fr;
  if constexpr (MODE == 0) {
    #pragma unroll
    for (int m = 0; m < 4; m++)
      #pragma unroll
      for (int n = 0; n < 4; n++)
        #pragma unroll
        for (int r = 0; r < 4; r++)
          C1[(size_t)(crow + m*16 + r) * N + (ccol + n*16)] = (f16)acc[m][n][r];
  } else if constexpr (MODE == 1) {
    f16* Cp = (bn < 4) ? C1 : C2;
    const int cc = (bn & 3) * 256 + wc * 64 + fr;
    #pragma unroll
    for (int m = 0; m < 4; m++)
      #pragma unroll
      for (int n = 0; n < 4; n++)
        #pragma unroll
        for (int r = 0; r < 4; r++)
          Cp[(size_t)(crow + m*16 + r) * 1024 + (cc + n*16)] = (f16)acc[m][n][r];
  } else {
    #pragma unroll
    for (int n = 0; n < 4; n++) {
      float bb = bias[ccol + n*16];
      #pragma unroll
      for (int m = 0; m < 4; m++)
        #pragma unroll
        for (int r = 0; r < 4; r++)
          Cf[(size_t)(crow + m*16 + r) * N + (ccol + n*16)] = acc[m][n][r] + bb;
    }
  }
}

// ---------------- per-graph 21x21 mix + fused BN partial stats --------------
// One f16x2 channel-pair per thread, no outer loop (VGPR-pressure lesson r4).
__global__ __launch_bounds__(256)
void k_mix(f16* __restrict__ t, const float* __restrict__ Aadj,
           float* __restrict__ psum, float* __restrict__ psq, int C) {
  __shared__ float A[441];
  int b = blockIdx.x, tid = threadIdx.x;
  for (int i = tid; i < 441; i += 256) A[i] = Aadj[i];
  __syncthreads();
  int c0 = (blockIdx.y * 256 + tid) * 2;
  size_t base = (size_t)b * NN * C + c0;
  float vx[21], vy[21];
  #pragma unroll
  for (int j = 0; j < 21; j++) {
    f16x2 v = *(const f16x2*)(t + base + (size_t)j * C);
    vx[j] = (float)v[0]; vy[j] = (float)v[1];
  }
  float s0 = 0.f, s1 = 0.f, q0 = 0.f, q1 = 0.f;
  #pragma unroll
  for (int i = 0; i < 21; i++) {
    float a0 = 0.f, a1 = 0.f;
    #pragma unroll
    for (int j = 0; j < 21; j++) {
      float w = A[i*21 + j];
      a0 = fmaf(w, vx[j], a0);
      a1 = fmaf(w, vy[j], a1);
    }
    f16x2 o; o[0] = (f16)a0; o[1] = (f16)a1;
    *(f16x2*)(t + base + (size_t)i * C) = o;
    s0 += a0; s1 += a1;
    q0 = fmaf(a0, a0, q0); q1 = fmaf(a1, a1, q1);
  }
  float2 sv; sv.x = s0; sv.y = s1;
  float2 qv; qv.x = q0; qv.y = q1;
  *(float2*)(psum + (size_t)b * C + c0) = sv;
  *(float2*)(psq  + (size_t)b * C + c0) = qv;
}

// ---------------- reduce 4096 graph-partials -> 32 (deterministic) ----------
__global__ void k_reduce(const float* __restrict__ ps, const float* __restrict__ pq,
                         float* __restrict__ rs, float* __restrict__ rq, int C) {
  int c = blockIdx.x * 256 + threadIdx.x;
  int py = blockIdx.y;                 // 0..31
  float s = 0.f, q = 0.f;
  for (int p = py*128; p < py*128 + 128; p++) {
    s += ps[(size_t)p*C + c];
    q += pq[(size_t)p*C + c];
  }
  rs[(size_t)py*C + c] = s;
  rq[(size_t)py*C + c] = q;
}

__global__ void k_bnparams(const float* __restrict__ psum, const float* __restrict__ psq,
                           const float* __restrict__ gamma, const float* __restrict__ beta,
                           const float* __restrict__ resbias,
                           float* __restrict__ scale, float* __restrict__ shift,
                           int C, int npart) {
  int c = blockIdx.x * 256 + threadIdx.x;
  float s = 0.f, q = 0.f;
  for (int p = 0; p < npart; p++) { s += psum[(size_t)p*C + c]; q += psq[(size_t)p*C + c]; }
  const float Minv = 1.f / (float)MROWS;
  float mean = s * Minv;
  float var = q * Minv - mean * mean;
  float sc = gamma[c] * rsqrtf(var + 1e-5f);
  float sh = beta[c] - mean * sc;
  if (resbias) sh += resbias[c];
  scale[c] = sc; shift[c] = sh;
}

// ---------------- finalize: dst = relu(g*scale + shift + res) ----------------
__global__ void k_finalize(const f16* __restrict__ g, const f16* __restrict__ res,
                           f16* __restrict__ dst, const float* __restrict__ scale,
                           const float* __restrict__ shift, int cmask) {
  size_t i8 = (size_t)blockIdx.x * 256 + threadIdx.x;
  size_t base = i8 * 8;
  int c = (int)(base & (size_t)cmask);
  f16x8 gv = *(const f16x8*)(g + base);
  f16x8 rv = *(const f16x8*)(res + base);
  f16x8 o;
  #pragma unroll
  for (int j = 0; j < 8; j++) {
    float v = (float)gv[j] * scale[c + j] + shift[c + j] + (float)rv[j];
    o[j] = (f16)fmaxf(v, 0.f);
  }
  *(f16x8*)(dst + base) = o;
}

// ---------------- pool (mean over 21) + BN affine -> f16 ----------------
__global__ void k_pool(const f16* __restrict__ g3, const float* __restrict__ scale,
                       const float* __restrict__ shift, f16* __restrict__ pooled) {
  int b = blockIdx.x, t = threadIdx.x;
  for (int c = t; c < COUTC; c += 256) {
    float s = 0.f;
    #pragma unroll
    for (int n = 0; n < NN; n++) s += (float)g3[((size_t)b*NN + n)*COUTC + c];
    pooled[(size_t)b*COUTC + c] = (f16)((s * (1.f/21.f)) * scale[c] + shift[c]);
  }
}

extern "C" void kernel_launch(void* const* d_in, const int* in_sizes, int n_in,
                              void* d_out, int out_size, void* d_ws, size_t ws_size,
                              hipStream_t stream) {
  const float* x     = (const float*)d_in[0];
  const float* nv1   = (const float*)d_in[2];
  const float* nv2   = (const float*)d_in[3];
  const float* se_w1 = (const float*)d_in[4];
  const float* se_w2 = (const float*)d_in[5];
  const float* W1    = (const float*)d_in[6];
  const float* W2    = (const float*)d_in[8];
  const float* W3    = (const float*)d_in[10];
  const float* bn1g  = (const float*)d_in[12];
  const float* bn1b  = (const float*)d_in[13];
  const float* bn2g  = (const float*)d_in[14];
  const float* bn2b  = (const float*)d_in[15];
  const float* bn3g  = (const float*)d_in[16];
  const float* bn3b  = (const float*)d_in[17];
  const float* rs1w  = (const float*)d_in[18];
  const float* rs1b  = (const float*)d_in[19];
  const float* fcw   = (const float*)d_in[20];
  const float* fcb   = (const float*)d_in[21];
  float* out = (float*)d_out;

  char* ws = (char*)d_ws;
  size_t off = 0;
  auto alloc = [&](size_t bytes) -> char* {
    char* p = ws + off;
    off = (off + bytes + 255) & ~(size_t)255;
    return p;
  };

  float* A_adj = (float*)alloc(441 * 4);
  f16* W1R  = (f16*)alloc((size_t)2048 * CIN * 2);       // [W1T ; RS1T]
  f16* W2T  = (f16*)alloc((size_t)H2C * H1C * 2);
  f16* W3T  = (f16*)alloc((size_t)COUTC * H2C * 2);
  f16* FCWT = (f16*)alloc((size_t)1024 * COUTC * 2);
  float* xm = (float*)alloc((size_t)NB * CIN * 4);
  float* y1 = (float*)alloc((size_t)NB * 128 * 4);
  float* yv = (float*)alloc((size_t)NB * CIN * 4);
  float* psum = (float*)alloc((size_t)NB * 1024 * 4);    // per-graph partials
  float* psq  = (float*)alloc((size_t)NB * 1024 * 4);
  float* rsum = (float*)alloc((size_t)32 * 1024 * 4);
  float* rsq  = (float*)alloc((size_t)32 * 1024 * 4);
  float* sc1 = (float*)alloc(1024 * 4);
  float* sh1 = (float*)alloc(1024 * 4);
  float* sc2 = (float*)alloc(1024 * 4);
  float* sh2 = (float*)alloc(1024 * 4);
  float* sc3 = (float*)alloc(1024 * 4);
  float* sh3 = (float*)alloc(1024 * 4);
  f16* pooled = (f16*)alloc((size_t)NB * COUTC * 2);
  f16* P1 = (f16*)alloc((size_t)MROWS * 512 * 2);    // xg -> t3/g3
  f16* P2 = (f16*)alloc((size_t)MROWS * 1024 * 2);   // t1/g1 -> t2/g2 -> h2
  f16* P3 = (f16*)alloc((size_t)MROWS * 1024 * 2);   // r1 -> h1
  (void)ws_size; (void)in_sizes; (void)n_in; (void)out_size;

  // adjacency + weight transposes
  k_adj<<<1, 512, 0, stream>>>(nv1, nv2, A_adj);
  k_transpose<<<dim3(32, 16), dim3(32, 8), 0, stream>>>(W1,   W1R,                    512, 1024);
  k_transpose<<<dim3(32, 16), dim3(32, 8), 0, stream>>>(rs1w, W1R + (size_t)1024*512, 512, 1024);
  k_transpose<<<dim3(32, 32), dim3(32, 8), 0, stream>>>(W2,   W2T,  1024, 1024);
  k_transpose<<<dim3(16, 32), dim3(32, 8), 0, stream>>>(W3,   W3T,  1024, 512);
  k_transpose<<<dim3(32, 16), dim3(32, 8), 0, stream>>>(fcw,  FCWT, 512, 1024);

  // SE path
  k_mean<<<NB, 256, 0, stream>>>(x, xm);
  k_se1<<<NB, 128, 0, stream>>>(xm, se_w1, y1);
  k_se2<<<NB, 512, 0, stream>>>(y1, se_w2, yv);
  k_gate<<<21504, 256, 0, stream>>>(x, yv, P1);

  // layer 1: fused dual GEMM (t1 -> P2, r1 -> P3); M-tiles=672, N-tiles=8
  k_gemm8<1><<<672*8, 512, 0, stream>>>(P1, W1R, P2, P3, nullptr, nullptr, 2048, 512, 3);
  k_mix<<<dim3(NB, 2), 256, 0, stream>>>(P2, A_adj, psum, psq, 1024);
  k_reduce<<<dim3(4, 32), 256, 0, stream>>>(psum, psq, rsum, rsq, 1024);
  k_bnparams<<<4, 256, 0, stream>>>(rsum, rsq, bn1g, bn1b, rs1b, sc1, sh1, 1024, 32);
  k_finalize<<<43008, 256, 0, stream>>>(P2, P3, P3, sc1, sh1, 1023);   // h1 -> P3

  // layer 2: N-tiles=4
  k_gemm8<0><<<672*4, 512, 0, stream>>>(P3, W2T, P2, nullptr, nullptr, nullptr, 1024, 1024, 2);
  k_mix<<<dim3(NB, 2), 256, 0, stream>>>(P2, A_adj, psum, psq, 1024);
  k_reduce<<<dim3(4, 32), 256, 0, stream>>>(psum, psq, rsum, rsq, 1024);
  k_bnparams<<<4, 256, 0, stream>>>(rsum, rsq, bn2g, bn2b, nullptr, sc2, sh2, 1024, 32);
  k_finalize<<<43008, 256, 0, stream>>>(P2, P3, P2, sc2, sh2, 1023);   // h2 -> P2

  // layer 3: N-tiles=2
  k_gemm8<0><<<672*2, 512, 0, stream>>>(P2, W3T, P1, nullptr, nullptr, nullptr, 512, 1024, 1);
  k_mix<<<dim3(NB, 1), 256, 0, stream>>>(P1, A_adj, psum, psq, 512);
  k_reduce<<<dim3(2, 32), 256, 0, stream>>>(psum, psq, rsum, rsq, 512);
  k_bnparams<<<2, 256, 0, stream>>>(rsum, rsq, bn3g, bn3b, nullptr, sc3, sh3, 512, 32);

  // pool + fc (MFMA): M-tiles=32, N-tiles=4
  k_pool<<<NB, 256, 0, stream>>>(P1, sc3, sh3, pooled);
  k_gemm8<2><<<32*4, 512, 0, stream>>>(pooled, FCWT, nullptr, nullptr, fcb, out, 1024, 512, 2);
}

// Round 8
// 1186.070 us; speedup vs baseline: 4.3191x; 1.0245x over previous
//
#include <hip/hip_runtime.h>

typedef _Float16 f16;
typedef f16 f16x2 __attribute__((ext_vector_type(2)));
typedef f16 f16x8 __attribute__((ext_vector_type(8)));
typedef float f32x4 __attribute__((ext_vector_type(4)));
typedef const void __attribute__((address_space(1)))* gas1;
typedef void __attribute__((address_space(3)))* las3;

#define NB 4096
#define NN 21
#define MROWS (NB*NN)      // 86016
#define CIN 512

// ---------------- adjacency ----------------
__global__ void k_adj(const float* __restrict__ nv1, const float* __restrict__ nv2,
                      float* __restrict__ Aout) {
  __shared__ float at[21][21];
  __shared__ float dinv[21];
  int t = threadIdx.x;
  if (t < 441) {
    int i = t / 21, j = t % 21;
    float s = 0.f;
    #pragma unroll
    for (int r = 0; r < 10; r++) s += nv1[i*10 + r] * nv2[r*21 + j];
    float v = 1.f / (1.f + expf(-s));
    if (i == j) v += 1.f;
    at[i][j] = v;
  }
  __syncthreads();
  if (t < 21) {
    float d = 0.f;
    #pragma unroll
    for (int j = 0; j < 21; j++) d += at[t][j];
    dinv[t] = d > 0.f ? rsqrtf(d) : 0.f;
  }
  __syncthreads();
  if (t < 441) {
    int i = t / 21, j = t % 21;
    float a = dinv[i] * at[i][j] * dinv[j];
    Aout[t] = a > 0.1f ? a : 0.f;
  }
}

// ---------------- transpose f32 [K][N] -> f16 [N][K] ----------------
__global__ void k_transpose(const float* __restrict__ src, f16* __restrict__ dst,
                            int K, int N) {
  __shared__ float tile[32][33];
  int n0 = blockIdx.x * 32, k0 = blockIdx.y * 32;
  int tx = threadIdx.x, ty = threadIdx.y;   // (32,8)
  #pragma unroll
  for (int i = 0; i < 4; i++)
    tile[ty + 8*i][tx] = src[(size_t)(k0 + ty + 8*i) * N + n0 + tx];
  __syncthreads();
  #pragma unroll
  for (int i = 0; i < 4; i++)
    dst[(size_t)(n0 + ty + 8*i) * K + k0 + tx] = (f16)tile[tx][ty + 8*i];
}

// ---------------- node mean over 21 ----------------
__global__ void k_mean(const float* __restrict__ x, float* __restrict__ xm) {
  int b = blockIdx.x, t = threadIdx.x;
  for (int c = t; c < CIN; c += 256) {
    float s = 0.f;
    #pragma unroll
    for (int n = 0; n < NN; n++) s += x[((size_t)b*NN + n)*CIN + c];
    xm[(size_t)b*CIN + c] = s * (1.f/21.f);
  }
}

// ---------------- SE matmuls ----------------
__global__ void k_se1(const float* __restrict__ xm, const float* __restrict__ w1,
                      float* __restrict__ y1) {
  __shared__ float row[CIN];
  int b = blockIdx.x, t = threadIdx.x;   // 128 threads
  for (int k = t; k < CIN; k += 128) row[k] = xm[(size_t)b*CIN + k];
  __syncthreads();
  float acc = 0.f;
  for (int k = 0; k < CIN; k++) acc += row[k] * w1[(size_t)k*128 + t];
  y1[(size_t)b*128 + t] = fmaxf(acc, 0.f);
}

__global__ void k_se2(const float* __restrict__ y1, const float* __restrict__ w2,
                      float* __restrict__ y) {
  __shared__ float row[128];
  int b = blockIdx.x, t = threadIdx.x;   // 512 threads
  if (t < 128) row[t] = y1[(size_t)b*128 + t];
  __syncthreads();
  float acc = 0.f;
  for (int k = 0; k < 128; k++) acc += row[k] * w2[(size_t)k*CIN + t];
  y[(size_t)b*CIN + t] = 1.f / (1.f + expf(-acc));
}

// ---------------- gating: xg = f16(x * y[graph]) ----------------
__global__ void k_gate(const float* __restrict__ x, const float* __restrict__ y,
                       f16* __restrict__ xg) {
  size_t i8 = (size_t)blockIdx.x * 256 + threadIdx.x;
  size_t base = i8 * 8;
  int r = (int)(base >> 9);          // /512
  int c = (int)(base & 511);
  int b = r / 21;
  const float4* xp = (const float4*)(x + base);
  const float4* yp = (const float4*)(y + (size_t)b*CIN + c);
  float4 a0 = xp[0], a1 = xp[1];
  float4 g0 = yp[0], g1 = yp[1];
  f16x8 o;
  o[0] = (f16)(a0.x * g0.x); o[1] = (f16)(a0.y * g0.y);
  o[2] = (f16)(a0.z * g0.z); o[3] = (f16)(a0.w * g0.w);
  o[4] = (f16)(a1.x * g1.x); o[5] = (f16)(a1.y * g1.y);
  o[6] = (f16)(a1.z * g1.z); o[7] = (f16)(a1.w * g1.w);
  *(f16x8*)(xg + base) = o;
}

// ======== 8-wave pipelined GEMM: C[M][N] = A[M][K] @ BT[N][K]^T ========
// BM=128, BN=256, BK=64; 512 thr = 8 waves (2Mx4N), per-wave 64x64 out.
// Triple-buffered LDS (3x48KB); stage tile t+2 during tile t; counted vmcnt(6)
// mid-tile (exactly: tile t+1's 6 loads landed, tile t+2's 6 in flight).
// Fragment regs double-buffered (F0/F1) one k-slice ahead so every MFMA
// cluster's ds_reads were issued >= 1 cluster earlier. 2 barriers/K-tile,
// asm-volatile s_barrier (compiler memory fence; builtin is NOT one).
// T2 granule-XOR swizzle on global source + ds_read (LDS dest stays linear).
// MODE 0: f16 out. MODE 1: f16 out + fused BN column-stats partials per
// (m-block, col). MODE 2: f32 out + bias.
#define GBM 128
#define GBN 256
#define BUFB 49152

template<int MODE>
__global__ __launch_bounds__(512, 1)
void k_gemm8(const f16* __restrict__ A, const f16* __restrict__ BT,
             f16* __restrict__ C1, const float* __restrict__ bias,
             float* __restrict__ Cf, float* __restrict__ psum,
             float* __restrict__ psq, int N, int K, int lgn) {
  __shared__ __align__(16) char lds[3 * BUFB];
  const int tid = threadIdx.x;
  const int nwg = gridDim.x;
  const int g = blockIdx.x;
  const int swz = (g & 7) * (nwg >> 3) + (g >> 3);   // XCD-chunked, nwg%8==0
  const int bn = swz & ((1 << lgn) - 1);             // N fastest: A-panel L2 reuse
  const int bm = swz >> lgn;
  const int lane = tid & 63;
  const int wid = tid >> 6;
  const int wr = wid >> 2;          // 0..1
  const int wc = wid & 3;           // 0..3
  const int fr = lane & 15;
  const int kg = lane >> 4;         // 0..3

  // staging map: 6 x 16B granules/thread/K-tile (A: j=0..1, B: j=2..5)
  size_t srcOff[6]; int ldsOff[6];
  #pragma unroll
  for (int j = 0; j < 6; j++) {
    int gid = j * 512 + tid;
    if (gid < 1024) {               // A: 128 rows x 8 granules
      int row = gid >> 3, gr = gid & 7;
      int gsw = gr ^ (row & 7);     // pre-swizzled source granule
      srcOff[j] = (size_t)(bm * GBM + row) * K + gsw * 8;
      ldsOff[j] = gid * 16;         // linear dest (gload_lds requirement)
    } else {                        // B: 256 rows x 8 granules
      int bgid = gid - 1024;
      int row = bgid >> 3, gr = bgid & 7;
      int gsw = gr ^ (row & 7);
      srcOff[j] = (size_t)(bn * GBN + row) * K + gsw * 8;
      ldsOff[j] = 16384 + bgid * 16;
    }
  }

  // fragment byte bases + per-row swizzle keys
  int aOff[4], axor[4], bOff[4], bxor[4];
  #pragma unroll
  for (int m = 0; m < 4; m++) {
    int row = wr*64 + m*16 + fr;
    aOff[m] = row * 128; axor[m] = row & 7;
  }
  #pragma unroll
  for (int n = 0; n < 4; n++) {
    int row = wc*64 + n*16 + fr;
    bOff[n] = 16384 + row * 128; bxor[n] = row & 7;
  }

  f32x4 acc[4][4];
  #pragma unroll
  for (int m = 0; m < 4; m++)
    #pragma unroll
    for (int n = 0; n < 4; n++)
      #pragma unroll
      for (int r = 0; r < 4; r++) acc[m][n][r] = 0.f;

  auto STAGE3 = [&](int t2, int sbuf, int j0) {
    char* dst = (char*)lds + sbuf * BUFB;
    const size_t kof = (size_t)t2 * 64;
    #pragma unroll
    for (int j = 0; j < 3; j++) {
      int jj = j0 + j;
      const f16* src = (jj < 2 ? A : BT) + srcOff[jj] + kof;
      __builtin_amdgcn_global_load_lds((gas1)src, (las3)(dst + ldsOff[jj]), 16, 0, 0);
    }
  };
  auto READF = [&](f16x8* avv, f16x8* bvv, const char* rb, int s) {
    #pragma unroll
    for (int m = 0; m < 4; m++)
      avv[m] = *(const f16x8*)(rb + aOff[m] + (((s*4 + kg) ^ axor[m]) << 4));
    #pragma unroll
    for (int n = 0; n < 4; n++)
      bvv[n] = *(const f16x8*)(rb + bOff[n] + (((s*4 + kg) ^ bxor[n]) << 4));
  };

  f16x8 av0[4], bv0[4], av1[4], bv1[4];
  const int NT = K >> 6;
  // prologue: stage tiles 0,1; wait tile 0; preload F0 = (tile0, slice0)
  STAGE3(0, 0, 0); STAGE3(0, 0, 3);
  STAGE3(1, 1, 0); STAGE3(1, 1, 3);
  asm volatile("s_waitcnt vmcnt(6)" ::: "memory");
  asm volatile("s_barrier" ::: "memory");
  READF(av0, bv0, (const char*)lds, 0);

  for (int t = 0; t < NT; t++) {
    const char* rb  = (const char*)lds + (t % 3) * BUFB;
    const char* rbn = (const char*)lds + ((t + 1) % 3) * BUFB;
    const int sb = (t + 2) % 3;
    const bool stg  = (t + 2) < NT;
    const bool more = (t + 1) < NT;

    if (stg) STAGE3(t + 2, sb, 0);
    READF(av1, bv1, rb, 1);                      // (t, slice1) for later
    __builtin_amdgcn_s_setprio(1);
    #pragma unroll
    for (int m = 0; m < 4; m++)
      #pragma unroll
      for (int n = 0; n < 4; n++)
        acc[m][n] = __builtin_amdgcn_mfma_f32_16x16x32_f16(av0[m], bv0[n], acc[m][n], 0, 0, 0);
    __builtin_amdgcn_s_setprio(0);
    if (stg) STAGE3(t + 2, sb, 3);

    if (more) {
      if (stg) asm volatile("s_waitcnt vmcnt(6)" ::: "memory");
      else     asm volatile("s_waitcnt vmcnt(0)" ::: "memory");
      asm volatile("s_barrier" ::: "memory");    // all waves: tile t+1 resident
      READF(av0, bv0, rbn, 0);                   // (t+1, slice0) for next iter
    }
    __builtin_amdgcn_s_setprio(1);
    #pragma unroll
    for (int m = 0; m < 4; m++)
      #pragma unroll
      for (int n = 0; n < 4; n++)
        acc[m][n] = __builtin_amdgcn_mfma_f32_16x16x32_f16(av1[m], bv1[n], acc[m][n], 0, 0, 0);
    __builtin_amdgcn_s_setprio(0);
    asm volatile("s_barrier" ::: "memory");      // reads of buf[t] retired block-wide
  }

  const int crow = bm * GBM + wr * 64 + ((lane >> 4) << 2);
  const int ccol = bn * GBN + wc * 64 + fr;
  if constexpr (MODE == 2) {
    #pragma unroll
    for (int n = 0; n < 4; n++) {
      float bb = bias[ccol + n*16];
      #pragma unroll
      for (int m = 0; m < 4; m++)
        #pragma unroll
        for (int r = 0; r < 4; r++)
          Cf[(size_t)(crow + m*16 + r) * N + (ccol + n*16)] = acc[m][n][r] + bb;
    }
  } else {
    #pragma unroll
    for (int m = 0; m < 4; m++)
      #pragma unroll
      for (int n = 0; n < 4; n++)
        #pragma unroll
        for (int r = 0; r < 4; r++)
          C1[(size_t)(crow + m*16 + r) * N + (ccol + n*16)] = (f16)acc[m][n][r];
  }
  if constexpr (MODE == 1) {
    // fused BN column-stats: partial sum/sumsq over this block's 128 rows
    float s[4], q[4];
    #pragma unroll
    for (int n = 0; n < 4; n++) {
      float ss = 0.f, qq = 0.f;
      #pragma unroll
      for (int m = 0; m < 4; m++)
        #pragma unroll
        for (int r = 0; r < 4; r++) { float v = acc[m][n][r]; ss += v; qq = fmaf(v, v, qq); }
      s[n] = ss; q[n] = qq;
    }
    #pragma unroll
    for (int n = 0; n < 4; n++) {
      s[n] += __shfl_xor(s[n], 16); s[n] += __shfl_xor(s[n], 32);
      q[n] += __shfl_xor(q[n], 16); q[n] += __shfl_xor(q[n], 32);
    }
    float* wred = (float*)lds;   // 4 KB scratch, all staging drained by now
    if ((lane >> 4) == 0) {
      #pragma unroll
      for (int n = 0; n < 4; n++) {
        wred[wr*256 + wc*64 + n*16 + fr]       = s[n];
        wred[512 + wr*256 + wc*64 + n*16 + fr] = q[n];
      }
    }
    __syncthreads();
    if (tid < 256) {
      psum[(size_t)bm * N + bn*256 + tid] = wred[tid]       + wred[256 + tid];
      psq [(size_t)bm * N + bn*256 + tid] = wred[512 + tid] + wred[768 + tid];
    }
  }
}

// ---------------- in-place mix on [M][512] (xg -> mix(xg)) ----------------
__global__ __launch_bounds__(256)
void k_mixip(f16* __restrict__ t, const float* __restrict__ Aadj) {
  __shared__ float A[441];
  int b = blockIdx.x, tid = threadIdx.x;
  for (int i = tid; i < 441; i += 256) A[i] = Aadj[i];
  __syncthreads();
  int c0 = tid * 2;
  size_t base = (size_t)b * NN * 512 + c0;
  float vx[21], vy[21];
  #pragma unroll
  for (int j = 0; j < 21; j++) {
    f16x2 v = *(const f16x2*)(t + base + (size_t)j * 512);
    vx[j] = (float)v[0]; vy[j] = (float)v[1];
  }
  #pragma unroll
  for (int i = 0; i < 21; i++) {
    float a0 = 0.f, a1 = 0.f;
    #pragma unroll
    for (int j = 0; j < 21; j++) { float w = A[i*21+j]; a0 = fmaf(w, vx[j], a0); a1 = fmaf(w, vy[j], a1); }
    f16x2 o; o[0] = (f16)a0; o[1] = (f16)a1;
    *(f16x2*)(t + base + (size_t)i * 512) = o;
  }
}

// ------- per-graph 21x21 mix, in-place + per-graph BN stats (round-5) -------
__global__ __launch_bounds__(256)
void k_mix(f16* __restrict__ t, const float* __restrict__ Aadj,
           float* __restrict__ psum, float* __restrict__ psq, int C) {
  __shared__ float A[441];
  int b = blockIdx.x, tid = threadIdx.x;
  for (int i = tid; i < 441; i += 256) A[i] = Aadj[i];
  __syncthreads();
  int c0 = (blockIdx.y * 256 + tid) * 2;
  size_t base = (size_t)b * NN * C + c0;
  float vx[21], vy[21];
  #pragma unroll
  for (int j = 0; j < 21; j++) {
    f16x2 v = *(const f16x2*)(t + base + (size_t)j * C);
    vx[j] = (float)v[0]; vy[j] = (float)v[1];
  }
  float s0 = 0.f, s1 = 0.f, q0 = 0.f, q1 = 0.f;
  #pragma unroll
  for (int i = 0; i < 21; i++) {
    float a0 = 0.f, a1 = 0.f;
    #pragma unroll
    for (int j = 0; j < 21; j++) {
      float w = A[i*21 + j];
      a0 = fmaf(w, vx[j], a0);
      a1 = fmaf(w, vy[j], a1);
    }
    f16x2 o; o[0] = (f16)a0; o[1] = (f16)a1;
    *(f16x2*)(t + base + (size_t)i * C) = o;
    s0 += a0; s1 += a1;
    q0 = fmaf(a0, a0, q0); q1 = fmaf(a1, a1, q1);
  }
  float2 sv; sv.x = s0; sv.y = s1;
  float2 qv; qv.x = q0; qv.y = q1;
  *(float2*)(psum + (size_t)b * C + c0) = sv;
  *(float2*)(psq  + (size_t)b * C + c0) = qv;
}

// ---------------- reduce partials -> 32 groups (deterministic) --------------
__global__ void k_reduce(const float* __restrict__ ps, const float* __restrict__ pq,
                         float* __restrict__ rs, float* __restrict__ rq,
                         int C, int per) {
  int c = blockIdx.x * 256 + threadIdx.x;
  int py = blockIdx.y;                 // 0..31
  float s = 0.f, q = 0.f;
  for (int p = py*per; p < py*per + per; p++) {
    s += ps[(size_t)p*C + c];
    q += pq[(size_t)p*C + c];
  }
  rs[(size_t)py*C + c] = s;
  rq[(size_t)py*C + c] = q;
}

__global__ void k_bnparams(const float* __restrict__ psum, const float* __restrict__ psq,
                           const float* __restrict__ gamma, const float* __restrict__ beta,
                           const float* __restrict__ resbias,
                           float* __restrict__ scale, float* __restrict__ shift,
                           int C, int npart) {
  int c = blockIdx.x * 256 + threadIdx.x;
  float s = 0.f, q = 0.f;
  for (int p = 0; p < npart; p++) { s += psum[(size_t)p*C + c]; q += psq[(size_t)p*C + c]; }
  const float Minv = 1.f / (float)MROWS;
  float mean = s * Minv;
  float var = q * Minv - mean * mean;
  float sc = gamma[c] * rsqrtf(var + 1e-5f);
  float sh = beta[c] - mean * sc;
  if (resbias) sh += resbias[c];
  scale[c] = sc; shift[c] = sh;
}

// ---------------- finalize: dst = relu(g*scale + shift + res) ----------------
__global__ void k_finalize(const f16* __restrict__ g, const f16* res,
                           f16* dst, const float* __restrict__ scale,
                           const float* __restrict__ shift, int cmask) {
  size_t i8 = (size_t)blockIdx.x * 256 + threadIdx.x;
  size_t base = i8 * 8;
  int c = (int)(base & (size_t)cmask);
  f16x8 gv = *(const f16x8*)(g + base);
  f16x8 rv = *(const f16x8*)(res + base);
  f16x8 o;
  #pragma unroll
  for (int j = 0; j < 8; j++) {
    float v = (float)gv[j] * scale[c + j] + shift[c + j] + (float)rv[j];
    o[j] = (f16)fmaxf(v, 0.f);
  }
  *(f16x8*)(dst + base) = o;
}

// ---------------- fused finish + mix: hmix = mix(relu(t*sc+sh+res)) ---------
// hmix may alias t (per-thread column ownership; all t/res reads precede writes).
__global__ __launch_bounds__(256)
void k_finmix(const f16* t, const f16* res, f16* hout, f16* hmix,
              const float* __restrict__ scale, const float* __restrict__ shift,
              const float* __restrict__ Aadj, int C) {
  __shared__ float A[441];
  int b = blockIdx.x, tid = threadIdx.x;
  for (int i = tid; i < 441; i += 256) A[i] = Aadj[i];
  __syncthreads();
  int c0 = (blockIdx.y * 256 + tid) * 2;
  float scx = scale[c0], scy = scale[c0+1];
  float shx = shift[c0], shy = shift[c0+1];
  size_t base = (size_t)b * NN * C + c0;
  float hx[21], hy[21];
  #pragma unroll
  for (int j = 0; j < 21; j++) {
    f16x2 tv = *(const f16x2*)(t + base + (size_t)j*C);
    f16x2 rv = *(const f16x2*)(res + base + (size_t)j*C);
    hx[j] = fmaxf((float)tv[0]*scx + shx + (float)rv[0], 0.f);
    hy[j] = fmaxf((float)tv[1]*scy + shy + (float)rv[1], 0.f);
    if (hout) {
      f16x2 o; o[0] = (f16)hx[j]; o[1] = (f16)hy[j];
      *(f16x2*)(hout + base + (size_t)j*C) = o;
    }
  }
  #pragma unroll
  for (int i = 0; i < 21; i++) {
    float a0 = 0.f, a1 = 0.f;
    #pragma unroll
    for (int j = 0; j < 21; j++) { float w = A[i*21+j]; a0 = fmaf(w, hx[j], a0); a1 = fmaf(w, hy[j], a1); }
    f16x2 o; o[0] = (f16)a0; o[1] = (f16)a1;
    *(f16x2*)(hmix + base + (size_t)i*C) = o;
  }
}

// ---------------- pool (mean over 21) + BN affine -> f16 ----------------
__global__ void k_pool(const f16* __restrict__ g3, const float* __restrict__ scale,
                       const float* __restrict__ shift, f16* __restrict__ pooled) {
  int b = blockIdx.x, t = threadIdx.x;
  for (int c = t; c < 512; c += 256) {
    float s = 0.f;
    #pragma unroll
    for (int n = 0; n < NN; n++) s += (float)g3[((size_t)b*NN + n)*512 + c];
    pooled[(size_t)b*512 + c] = (f16)((s * (1.f/21.f)) * scale[c] + shift[c]);
  }
}

extern "C" void kernel_launch(void* const* d_in, const int* in_sizes, int n_in,
                              void* d_out, int out_size, void* d_ws, size_t ws_size,
                              hipStream_t stream) {
  const float* x     = (const float*)d_in[0];
  const float* nv1   = (const float*)d_in[2];
  const float* nv2   = (const float*)d_in[3];
  const float* se_w1 = (const float*)d_in[4];
  const float* se_w2 = (const float*)d_in[5];
  const float* W1    = (const float*)d_in[6];
  const float* W2    = (const float*)d_in[8];
  const float* W3    = (const float*)d_in[10];
  const float* bn1g  = (const float*)d_in[12];
  const float* bn1b  = (const float*)d_in[13];
  const float* bn2g  = (const float*)d_in[14];
  const float* bn2b  = (const float*)d_in[15];
  const float* bn3g  = (const float*)d_in[16];
  const float* bn3b  = (const float*)d_in[17];
  const float* rs1w  = (const float*)d_in[18];
  const float* rs1b  = (const float*)d_in[19];
  const float* fcw   = (const float*)d_in[20];
  const float* fcb   = (const float*)d_in[21];
  float* out = (float*)d_out;

  char* ws = (char*)d_ws;
  size_t off = 0;
  auto alloc = [&](size_t bytes) -> char* {
    char* p = ws + off;
    off = (off + bytes + 255) & ~(size_t)255;
    return p;
  };

  // total ws footprint ~484 MB (round 6's proven 500 MB was OK; round 7's
  // 738 MB aborted -> keep under the known-good bound).
  float* A_adj = (float*)alloc(441 * 4);
  f16* W1T  = (f16*)alloc((size_t)1024 * 512 * 2);
  f16* RS1T = (f16*)alloc((size_t)1024 * 512 * 2);
  f16* W2T  = (f16*)alloc((size_t)1024 * 1024 * 2);
  f16* W3T  = (f16*)alloc((size_t)512 * 1024 * 2);
  f16* FCWT = (f16*)alloc((size_t)1024 * 512 * 2);
  float* psum = (float*)alloc((size_t)NB * 1024 * 4);    // 16MB; aliases xm
  float* psq  = (float*)alloc((size_t)NB * 1024 * 4);    // 16MB; aliases yv
  float* y1   = (float*)alloc((size_t)NB * 128 * 4);
  float* rsum = (float*)alloc((size_t)32 * 1024 * 4);
  float* rsq  = (float*)alloc((size_t)32 * 1024 * 4);
  float* sc1 = (float*)alloc(1024 * 4);
  float* sh1 = (float*)alloc(1024 * 4);
  float* sc2 = (float*)alloc(1024 * 4);
  float* sh2 = (float*)alloc(1024 * 4);
  float* sc3 = (float*)alloc(1024 * 4);
  float* sh3 = (float*)alloc(1024 * 4);
  f16* pooled = (f16*)alloc((size_t)NB * 512 * 2);
  f16* G = (f16*)alloc((size_t)MROWS * 512 * 2);     // xg -> xgm -> T3
  f16* R = (f16*)alloc((size_t)MROWS * 1024 * 2);    // R1 -> h1
  f16* T = (f16*)alloc((size_t)MROWS * 1024 * 2);    // T1 -> T2/t2m -> h2m
  float* xm = psum;   // dead before psum first written (layer-1 T1 GEMM)
  float* yv = psq;    // dead after k_gate, before psq first written
  (void)ws_size; (void)in_sizes; (void)n_in; (void)out_size;

  // adjacency + weight transposes
  k_adj<<<1, 512, 0, stream>>>(nv1, nv2, A_adj);
  k_transpose<<<dim3(32, 16), dim3(32, 8), 0, stream>>>(W1,   W1T,  512, 1024);
  k_transpose<<<dim3(32, 16), dim3(32, 8), 0, stream>>>(rs1w, RS1T, 512, 1024);
  k_transpose<<<dim3(32, 32), dim3(32, 8), 0, stream>>>(W2,   W2T,  1024, 1024);
  k_transpose<<<dim3(16, 32), dim3(32, 8), 0, stream>>>(W3,   W3T,  1024, 512);
  k_transpose<<<dim3(32, 16), dim3(32, 8), 0, stream>>>(fcw,  FCWT, 512, 1024);

  // SE path + gate
  k_mean<<<NB, 256, 0, stream>>>(x, xm);
  k_se1<<<NB, 128, 0, stream>>>(xm, se_w1, y1);
  k_se2<<<NB, 512, 0, stream>>>(y1, se_w2, yv);
  k_gate<<<21504, 256, 0, stream>>>(x, yv, G);

  // layer 1: R1 = xg@rs1w; xgm = mix(xg) in place; T1 = xgm@W1 (+fused stats)
  k_gemm8<0><<<672*4, 512, 0, stream>>>(G, RS1T, R, nullptr, nullptr, nullptr, nullptr, 1024, 512, 2);
  k_mixip<<<NB, 256, 0, stream>>>(G, A_adj);
  k_gemm8<1><<<672*4, 512, 0, stream>>>(G, W1T, T, nullptr, nullptr, psum, psq, 1024, 512, 2);
  k_reduce<<<dim3(4, 32), 256, 0, stream>>>(psum, psq, rsum, rsq, 1024, 21);
  k_bnparams<<<4, 256, 0, stream>>>(rsum, rsq, bn1g, bn1b, rs1b, sc1, sh1, 1024, 32);
  k_finalize<<<43008, 256, 0, stream>>>(T, R, R, sc1, sh1, 1023);     // h1 -> R

  // layer 2: T2 = h1@W2; mix+stats in place; h2m = mix(relu(BN(t2m)+h1)) -> T
  k_gemm8<0><<<672*4, 512, 0, stream>>>(R, W2T, T, nullptr, nullptr, nullptr, nullptr, 1024, 1024, 2);
  k_mix<<<dim3(NB, 2), 256, 0, stream>>>(T, A_adj, psum, psq, 1024);
  k_reduce<<<dim3(4, 32), 256, 0, stream>>>(psum, psq, rsum, rsq, 1024, 128);
  k_bnparams<<<4, 256, 0, stream>>>(rsum, rsq, bn2g, bn2b, nullptr, sc2, sh2, 1024, 32);
  k_finmix<<<dim3(NB, 2), 256, 0, stream>>>(T, R, nullptr, T, sc2, sh2, A_adj, 1024);

  // layer 3: T3 = h2m@W3 (+fused stats) -> G
  k_gemm8<1><<<672*2, 512, 0, stream>>>(T, W3T, G, nullptr, nullptr, psum, psq, 512, 1024, 1);
  k_reduce<<<dim3(2, 32), 256, 0, stream>>>(psum, psq, rsum, rsq, 512, 21);
  k_bnparams<<<2, 256, 0, stream>>>(rsum, rsq, bn3g, bn3b, nullptr, sc3, sh3, 512, 32);

  // pool + fc
  k_pool<<<NB, 256, 0, stream>>>(G, sc3, sh3, pooled);
  k_gemm8<2><<<32*4, 512, 0, stream>>>(pooled, FCWT, nullptr, fcb, out, nullptr, nullptr, 1024, 512, 2);
}